// Round 4
// baseline (910.952 us; speedup 1.0000x reference)
//
#include <hip/hip_runtime.h>
#include <math.h>

#define DI __device__ __forceinline__
typedef unsigned short ush;

DI float u2f(ush u){ return __uint_as_float(((unsigned int)u)<<16); }
DI ush f2u(float f){ unsigned int u=__float_as_uint(f); u += 0x7fffu + ((u>>16)&1u); return (ush)(u>>16); }

constexpr int HWc = 4096;
constexpr float RCNT = 1.f/131072.f;      // 1 / (N*H*W)
constexpr size_t BIG = 33554432ull;       // [32][128][4096] bf16 bytes

typedef __attribute__((ext_vector_type(8))) __bf16 bf8;
typedef __attribute__((ext_vector_type(4))) float  f4;

// ---------------- K0: zero a float block -----------------------------------
__global__ void k_zero(float* __restrict__ s, int n){
  int i=blockIdx.x*256+threadIdx.x;
  if(i<n) s[i]=0.f;
}

// ---------------- fallback: zero-fill output (clean diagnostic failure) ----
__global__ void k_trivial(float* __restrict__ out){
  size_t i=(size_t)blockIdx.x*256+threadIdx.x;
  if(i<16777216ull) out[i]=0.f;
}

// ---------------- K1: per-pixel channel mean/max ---------------------------
__global__ void k_chan_reduce(const float* __restrict__ x, float* __restrict__ smean, float* __restrict__ smax){
  int n = blockIdx.y;
  int px = blockIdx.x*256 + threadIdx.x;
  const float* xp = x + ((size_t)n*128)*HWc + px;
  float s=0.f, m=-INFINITY;
  #pragma unroll 8
  for(int c=0;c<128;c++){ float v=xp[(size_t)c*HWc]; s+=v; m=fmaxf(m,v); }
  smean[n*HWc+px]=s*(1.f/128.f);
  smax[n*HWc+px]=m;
}

// ---------------- K2: 7x7 conv (2->1 ch) + sigmoid -> sa -------------------
__global__ void k_sa(const float* __restrict__ smean, const float* __restrict__ smax,
                     const float* __restrict__ w, float* __restrict__ sa){
  __shared__ float wm[49], wx[49];
  int t=threadIdx.x;
  if(t<49) wm[t]=w[t];
  else if(t<98) wx[t-49]=w[t];
  __syncthreads();
  int n=blockIdx.y;
  int px=blockIdx.x*256+t;
  int r=px>>6, c=px&63;
  const float* pm  = smean + n*HWc;
  const float* pxm = smax  + n*HWc;
  float acc=0.f;
  for(int ky=0;ky<7;ky++){
    int rr=r+ky-3; if(rr<0||rr>=64) continue;
    for(int kx=0;kx<7;kx++){
      int cc=c+kx-3; if(cc<0||cc>=64) continue;
      int q=(rr<<6)+cc;
      acc += wm[ky*7+kx]*pm[q] + wx[ky*7+kx]*pxm[q];
    }
  }
  sa[n*HWc+px] = 1.f/(1.f+expf(-acc));
}

// ---------------- K3: per-(n,c) sum/max over HW of x*sa --------------------
__global__ void k_rowred(const float* __restrict__ x, const float* __restrict__ sa,
                         float* __restrict__ rsum, float* __restrict__ rmax){
  int c=blockIdx.x, n=blockIdx.y;
  const float* xp = x + ((size_t)n*128 + c)*HWc;
  const float* sp = sa + n*HWc;
  float s=0.f, m=-INFINITY;
  for(int i=threadIdx.x;i<HWc;i+=256){
    float v=xp[i]*sp[i]; s+=v; m=fmaxf(m,v);
  }
  __shared__ float ls[4], lm[4];
  for(int o=32;o>0;o>>=1){ s+=__shfl_down(s,o,64); m=fmaxf(m,__shfl_down(m,o,64)); }
  int lane=threadIdx.x&63, wv=threadIdx.x>>6;
  if(lane==0){ ls[wv]=s; lm[wv]=m; }
  __syncthreads();
  if(threadIdx.x==0){
    rsum[n*128+c]=ls[0]+ls[1]+ls[2]+ls[3];
    rmax[n*128+c]=fmaxf(fmaxf(lm[0],lm[1]),fmaxf(lm[2],lm[3]));
  }
}

// ---------------- K4a: channel-attention MLP per n -------------------------
__global__ void k_mlp(const float* __restrict__ rsum, const float* __restrict__ rmax,
                      const float* __restrict__ fc1, const float* __restrict__ fc2,
                      float* __restrict__ att){
  int n=blockIdx.x, t=threadIdx.x;
  __shared__ float zm[128], zx[128], hm[64], hx[64];
  if(t<128){ zm[t]=rsum[n*128+t]*(1.f/4096.f); zx[t]=rmax[n*128+t]; }
  __syncthreads();
  if(t<64){
    float a=0.f;
    for(int c=0;c<128;c++) a+=fc1[t*128+c]*zm[c];
    hm[t]=fmaxf(a,0.f);
  } else if(t<128){
    int j=t-64; float a=0.f;
    for(int c=0;c<128;c++) a+=fc1[j*128+c]*zx[c];
    hx[j]=fmaxf(a,0.f);
  }
  __syncthreads();
  if(t<128){
    float a=0.f,b=0.f;
    for(int j=0;j<64;j++){ float wv=fc2[t*64+j]; a+=wv*hm[j]; b+=wv*hx[j]; }
    att[n*128+t]=1.f/(1.f+expf(-(a+b)));
  }
}

// ---------------- K4b: slist, top-96, num_dict, last-occurrence map --------
__global__ void k_topk(const float* __restrict__ att, const int* __restrict__ perm,
                       int* __restrict__ nd_out, int* __restrict__ dst_pos){
  __shared__ float sl[128];
  __shared__ int nd[128];
  int t=threadIdx.x;          // 128 threads
  float s=0.f;
  for(int n=0;n<32;n++) s+=att[n*128+t];
  sl[t]=s;
  nd[t]=t;
  __syncthreads();
  float v=sl[t]; int r=0;
  for(int c=0;c<128;c++){ float u=sl[c]; r += ((u>v) || (u==v && c<t)) ? 1 : 0; }
  if(r<96) nd[r]=t;
  __syncthreads();
  if(t<32) nd[96+t]=perm[t]&127;
  __syncthreads();
  nd_out[t]=nd[t]&127;
  int pos=-1;
  for(int p=0;p<128;p++) if((nd[p]&127)==t) pos=p;
  dst_pos[t]=pos;
}

// ---------------- zero the halo pad columns of a padded LDS plane ----------
template<int R,int S>
DI void stage_pads(float* __restrict__ Pl, int t){
  if(t<64){
    #pragma unroll
    for(int j=0;j<R;j++) Pl[t*S+j]=0.f;
    #pragma unroll
    for(int j=64+R;j<S;j++) Pl[t*S+j]=0.f;
  }
}

// ---------------- K6: bn stats of max_pool3(xt), avg_pool3(xt) -------------
// Register-tiled: thread owns 16-px row strip; 3 row-segment b128 load sets.
__global__ __launch_bounds__(256) void k_poolstats(const float* __restrict__ x,
    const float* __restrict__ sa, const float* __restrict__ att,
    const int* __restrict__ nd, float* __restrict__ stats){
  constexpr int S=68;
  __shared__ float Pl[64*S];
  int p=blockIdx.x, n=blockIdx.y, t=threadIdx.x;
  int chs=nd[p]&127;
  float a=att[n*128+chs];
  const float* xp = x + ((size_t)n*128+chs)*HWc;
  const float* sp = sa + n*HWc;
  #pragma unroll
  for(int k=0;k<16;k++){
    int px=t+k*256;
    Pl[(px>>6)*S + 1 + (px&63)] = xp[px]*sp[px]*a;
  }
  stage_pads<1,S>(Pl,t);
  __syncthreads();
  int r=t>>2, c0=(t&3)*16;
  float s[16], m[16];
  #pragma unroll
  for(int i=0;i<16;i++){ s[i]=0.f; m[i]=-INFINITY; }
  int rin=0;
  #pragma unroll
  for(int ky=-1;ky<=1;ky++){
    int rr=r+ky;
    if(rr<0||rr>=64) continue;
    rin++;
    float row[20];
    #pragma unroll
    for(int j=0;j<5;j++) *(float4*)&row[4*j] = *(const float4*)&Pl[rr*S + c0 + 4*j];
    // row[j] holds data col (c0-1+j); pads are zero.
    float e0  = (c0==0)  ? -INFINITY : row[0];
    float e17 = (c0==48) ? -INFINITY : row[17];
    #pragma unroll
    for(int i=0;i<16;i++){
      float lf = (i==0)  ? e0  : row[i];
      float rg = (i==15) ? e17 : row[i+2];
      s[i] += row[i]+row[i+1]+row[i+2];
      m[i] = fmaxf(m[i], fmaxf(lf, fmaxf(row[i+1], rg)));
    }
  }
  float sm=0,qm=0,sv=0,qv=0;
  #pragma unroll
  for(int i=0;i<16;i++){
    int c=c0+i;
    float cnt=(float)(rin*(3-(c==0)-(c==63)));
    float ap=s[i]/cnt, mp=m[i];
    sm+=mp; qm+=mp*mp; sv+=ap; qv+=ap*ap;
  }
  for(int o=32;o>0;o>>=1){
    sm+=__shfl_down(sm,o,64); qm+=__shfl_down(qm,o,64);
    sv+=__shfl_down(sv,o,64); qv+=__shfl_down(qv,o,64);
  }
  __shared__ float l[4][4];
  int lane=t&63, wv=t>>6;
  if(lane==0){ l[wv][0]=sm; l[wv][1]=qm; l[wv][2]=sv; l[wv][3]=qv; }
  __syncthreads();
  if(t==0){
    atomicAdd(&stats[p],     l[0][0]+l[1][0]+l[2][0]+l[3][0]);
    atomicAdd(&stats[128+p], l[0][1]+l[1][1]+l[2][1]+l[3][1]);
    atomicAdd(&stats[256+p], l[0][2]+l[1][2]+l[2][2]+l[3][2]);
    atomicAdd(&stats[384+p], l[0][3]+l[1][3]+l[2][3]+l[3][3]);
  }
}

// ---------------- K8a: base of output (register-tiled pool3) ---------------
__global__ __launch_bounds__(256) void k_base(const float* __restrict__ x,
    const float* __restrict__ sa, const float* __restrict__ att,
    const int* __restrict__ nd, const int* __restrict__ dpos,
    const float* __restrict__ stats, const float* __restrict__ wts,
    float* __restrict__ out){
  constexpr int S=68;
  __shared__ float Pl[64*S];
  int ch=blockIdx.x, n=blockIdx.y, t=threadIdx.x;
  int p=dpos[ch];                      // block-uniform branch
  const float* sp = sa + n*HWc;
  if(p<0){
    float a=att[n*128+ch];
    const float* xp = x + ((size_t)n*128+ch)*HWc;
    float* op = out + ((size_t)n*128+ch)*HWc;
    for(int px=t;px<HWc;px+=256) op[px]=xp[px]*sp[px]*a;
    return;
  }
  p&=127;
  int chs=nd[p]&127;
  float a=att[n*128+chs];
  const float* xp = x + ((size_t)n*128+chs)*HWc;
  #pragma unroll
  for(int k=0;k<16;k++){
    int px=t+k*256;
    Pl[(px>>6)*S + 1 + (px&63)] = xp[px]*sp[px]*a;
  }
  stage_pads<1,S>(Pl,t);
  __syncthreads();
  float w1=wts[1],w2=wts[2],w3=wts[3];
  float m0,r0v,m1,r1v;
  { float su=stats[p],     sq=stats[128+p]; float mean=su*RCNT,var=sq*RCNT-mean*mean; m0=mean; r0v=rsqrtf(var+1e-5f); }
  { float su=stats[256+p], sq=stats[384+p]; float mean=su*RCNT,var=sq*RCNT-mean*mean; m1=mean; r1v=rsqrtf(var+1e-5f); }
  int r=t>>2, c0=(t&3)*16;
  float s[16], m[16], crow[16];
  #pragma unroll
  for(int i=0;i<16;i++){ s[i]=0.f; m[i]=-INFINITY; }
  int rin=0;
  #pragma unroll
  for(int ky=-1;ky<=1;ky++){
    int rr=r+ky;
    if(rr<0||rr>=64) continue;
    rin++;
    float row[20];
    #pragma unroll
    for(int j=0;j<5;j++) *(float4*)&row[4*j] = *(const float4*)&Pl[rr*S + c0 + 4*j];
    if(ky==0){
      #pragma unroll
      for(int i=0;i<16;i++) crow[i]=row[i+1];
    }
    float e0  = (c0==0)  ? -INFINITY : row[0];
    float e17 = (c0==48) ? -INFINITY : row[17];
    #pragma unroll
    for(int i=0;i<16;i++){
      float lf = (i==0)  ? e0  : row[i];
      float rg = (i==15) ? e17 : row[i+2];
      s[i] += row[i]+row[i+1]+row[i+2];
      m[i] = fmaxf(m[i], fmaxf(lf, fmaxf(row[i+1], rg)));
    }
  }
  float* op = out + ((size_t)n*128+ch)*HWc + r*64 + c0;
  float v[16];
  #pragma unroll
  for(int i=0;i<16;i++){
    int c=c0+i;
    float cnt=(float)(rin*(3-(c==0)-(c==63)));
    float ap=s[i]/cnt;
    v[i] = w3*crow[i] + w1*(m[i]-m0)*r0v + w2*(ap-m1)*r1v;
  }
  #pragma unroll
  for(int q=0;q<4;q++) *(float4*)(op+4*q) = *(float4*)&v[4*q];
}

// ---------------- K_dw: depthwise conv on one (n,p) plane ------------------
// Register-tiled: thread owns 16-px row strip (r=t>>2, c0=(t&3)*16).
// Plane staged into LDS with zero-padded halo cols; per ky a row segment is
// pulled with ds_read_b128 into registers; KSx16 FMAs with static indices.
// SX=1: input = relu(x[nd[p]]*sa*att). SX=0: input = relu(bn(bf16 buf)),
// bn stats folded inline from the 32-way shard array (no k_statred pass).
template<int KS,int DIL,int SX>
__global__ __launch_bounds__(256) void k_dw(const float* __restrict__ xsrc,
    const ush* __restrict__ bufsrc, const float* __restrict__ dww,
    const float* __restrict__ shd, const float* __restrict__ sa,
    const float* __restrict__ att, const int* __restrict__ nd,
    ush* __restrict__ outb){
  constexpr int R=(KS/2)*DIL;          // halo reach: 1,2,2,4
  constexpr int S=(R==4)?76:68;        // stride = 4 mod 32 -> <=4-way banks, 16B-aligned
  constexpr int L=16+2*R;              // row floats needed
  constexpr int NL=(L+3)/4;            // float4 loads per row (5 or 6)
  __shared__ float Pl[64*S];
  int p=blockIdx.x, n=blockIdx.y, t=threadIdx.x;
  const float* sp = sa + n*HWc;
  if constexpr (SX){
    int ch=nd[p]&127;
    float a=att[n*128+ch];
    const float* xp = xsrc + ((size_t)n*128+ch)*HWc;
    #pragma unroll
    for(int k=0;k<16;k++){
      int px=t+k*256;
      Pl[(px>>6)*S + R + (px&63)] = fmaxf(xp[px]*sp[px]*a,0.f);
    }
  } else {
    float su=0.f,sq=0.f;
    #pragma unroll
    for(int j=0;j<32;j++){ su+=shd[j*256+p]; sq+=shd[j*256+128+p]; }
    float mean=su*RCNT, var=sq*RCNT-mean*mean, rstd=rsqrtf(var+1e-5f);
    const ush* bp = bufsrc + ((size_t)n*128+p)*HWc;
    #pragma unroll
    for(int k=0;k<16;k++){
      int px=t+k*256;
      Pl[(px>>6)*S + R + (px&63)] = fmaxf((u2f(bp[px])-mean)*rstd,0.f);
    }
  }
  stage_pads<R,S>(Pl,t);
  __syncthreads();
  float wk[KS*KS];
  #pragma unroll
  for(int i=0;i<KS*KS;i++) wk[i]=dww[p*KS*KS+i];
  int r=t>>2, c0=(t&3)*16;
  float acc[16];
  #pragma unroll
  for(int i=0;i<16;i++) acc[i]=0.f;
  #pragma unroll
  for(int ky=0;ky<KS;ky++){
    int rr=r+(ky-KS/2)*DIL;
    if(rr<0||rr>=64) continue;
    float row[NL*4];
    #pragma unroll
    for(int j=0;j<NL;j++) *(float4*)&row[4*j] = *(const float4*)&Pl[rr*S + c0 + 4*j];
    #pragma unroll
    for(int kx=0;kx<KS;kx++){
      float wv=wk[ky*KS+kx];
      #pragma unroll
      for(int i=0;i<16;i++) acc[i]+=wv*row[R + i + (kx-KS/2)*DIL];
    }
  }
  ush* op = outb + ((size_t)n*128+p)*HWc + r*64 + c0;
  #pragma unroll
  for(int q=0;q<4;q++){
    ushort4 vv;
    vv.x=f2u(acc[4*q+0]); vv.y=f2u(acc[4*q+1]);
    vv.z=f2u(acc[4*q+2]); vv.w=f2u(acc[4*q+3]);
    *(ushort4*)(op+4*q)=vv;
  }
}

// ---------------- K_wcvt: f32 -> bf16 weight convert (16384 elems) ---------
__global__ void k_cvt(const float* __restrict__ src, ush* __restrict__ dst){
  int i=blockIdx.x*256+threadIdx.x;
  dst[i]=f2u(src[i]);
}

// ---------------- K_pw_mfma: pointwise 128->128 MFMA GEMM + bn stats -------
// D[co][px] = sum_ci W[co][ci] * dwin[ci][px], bf16 in, f32 acc, bf16 out.
// Block: 256 thr = 4 waves; tile M=128(co) x N=64(px), K=128 (4 steps of 32).
// B staged in LDS TRANSPOSED: Bt[px][ci] (pad +4) -> plain 8B k-contiguous
// fragment reads (m92/m97-verified pattern). A-frags from global bf16.
// bn-stats partials go to 32-way SHARDED accumulators (Guideline 12).
__global__ __launch_bounds__(256) void k_pw_mfma(const ush* __restrict__ dwin,
    const ush* __restrict__ wt, ush* __restrict__ outb, float* __restrict__ shad){
  __shared__ ush Bt[64][132];          // 16.9 KiB, row stride 264 B
  int t=threadIdx.x, n=blockIdx.y;
  int px0b = blockIdx.x*64;

  const ush* dp = dwin + ((size_t)n*128)*HWc + px0b;
  // stage + transpose: thread handles ci pair (2*c2, 2*c2+1) x 4 px
  #pragma unroll
  for(int k=0;k<4;k++){
    int e = t + k*256;                 // [0,1024)
    int c2 = e>>4;                     // ci pair 0..63
    int p4 = (e&15)*4;                 // px 0..60 step 4
    const ush* g0 = dp + (size_t)(2*c2)*HWc + p4;
    ushort4 va = *(const ushort4*)g0;
    ushort4 vb = *(const ushort4*)(g0 + HWc);
    *(unsigned int*)&Bt[p4+0][2*c2] = (unsigned int)va.x | ((unsigned int)vb.x<<16);
    *(unsigned int*)&Bt[p4+1][2*c2] = (unsigned int)va.y | ((unsigned int)vb.y<<16);
    *(unsigned int*)&Bt[p4+2][2*c2] = (unsigned int)va.z | ((unsigned int)vb.z<<16);
    *(unsigned int*)&Bt[p4+3][2*c2] = (unsigned int)va.w | ((unsigned int)vb.w<<16);
  }

  int lane=t&63, wv=t>>6;
  int co0=(wv>>1)*64, pxw=(wv&1)*32;   // wave tile: 64 co x 32 px
  int g=lane>>4, sl=lane&15;
  // A fragments (verified layout): row(M)=co0+mt*16+sl, k=kt*32+g*8+j (j=0..7)
  int arow = co0 + sl;
  int acg  = g*8;
  bf8 a[4][4];
  #pragma unroll
  for(int mt=0;mt<4;mt++)
    #pragma unroll
    for(int kt=0;kt<4;kt++)
      a[mt][kt] = *(const bf8*)(wt + (size_t)(arow+mt*16)*128 + kt*32 + acg);

  f4 acc[4][2] = {};
  __syncthreads();

  #pragma unroll
  for(int nt=0;nt<2;nt++){
    int pxl = pxw + nt*16 + sl;        // col(N)=lane&15 within 16-px group
    bf8 b[4];
    #pragma unroll
    for(int kt=0;kt<4;kt++){
      union { uint2 h[2]; bf8 v; } u;
      const ush* bp = &Bt[pxl][kt*32 + acg];
      u.h[0] = *(const uint2*)bp;      // 8B-aligned (264*px + 64kt + 16g)
      u.h[1] = *(const uint2*)(bp+4);
      b[kt] = u.v;
    }
    #pragma unroll
    for(int kt=0;kt<4;kt++)
      #pragma unroll
      for(int mt=0;mt<4;mt++)
        acc[mt][nt] = __builtin_amdgcn_mfma_f32_16x16x32_bf16(a[mt][kt], b[kt], acc[mt][nt], 0,0,0);
  }

  // Epilogue: D layout col(px)=lane&15, row(co)=(lane>>4)*4+r. Store bf16 +
  // fused bn stats (sum, sumsq per co) via 16-lane reduce + sharded atomics.
  float* sh = shad + (((blockIdx.x + blockIdx.y)&31)*256);
  #pragma unroll
  for(int mt=0;mt<4;mt++){
    #pragma unroll
    for(int r=0;r<4;r++){
      int co = co0 + mt*16 + g*4 + r;
      float v0=acc[mt][0][r], v1=acc[mt][1][r];
      ush* ob = outb + ((size_t)n*128+co)*HWc + px0b + pxw;
      ob[sl]      = f2u(v0);
      ob[16+sl]   = f2u(v1);
      float s1 = v0+v1, s2 = v0*v0+v1*v1;
      #pragma unroll
      for(int o=1;o<16;o<<=1){ s1+=__shfl_xor(s1,o,64); s2+=__shfl_xor(s2,o,64); }
      if(sl==0){ atomicAdd(&sh[co],s1); atomicAdd(&sh[128+co],s2); }
    }
  }
}

// ---------------- K8b: out += w*(br-mean)*rstd for winning positions -------
// bn stats folded inline from the 32-way shard array (no k_statred pass).
__global__ void k_accum(const ush* __restrict__ br, const int* __restrict__ nd,
    const int* __restrict__ dpos, const float* __restrict__ shd,
    const float* __restrict__ wts, int widx, float* __restrict__ out){
  int n=blockIdx.z, p=blockIdx.y;
  int ch=nd[p]&127;
  if(dpos[ch]!=p) return;
  int px=blockIdx.x*256+threadIdx.x;
  float su=0.f, sq=0.f;
  #pragma unroll
  for(int j=0;j<32;j++){ su+=shd[j*256+p]; sq+=shd[j*256+128+p]; }
  float mean=su*RCNT, var=sq*RCNT-mean*mean, rstd=rsqrtf(var+1e-5f);
  float w=wts[widx];
  size_t oidx=((size_t)n*128+ch)*HWc+px;
  size_t bidx=((size_t)n*128+p)*HWc+px;
  out[oidx] += w*(u2f(br[bidx])-mean)*rstd;
}

extern "C" void kernel_launch(void* const* d_in, const int* in_sizes, int n_in,
                              void* d_out, int out_size, void* d_ws, size_t ws_size,
                              hipStream_t stream){
  (void)in_sizes; (void)n_in; (void)out_size;
  const float* x   =(const float*)d_in[0];
  const float* wts =(const float*)d_in[1];
  const float* fc1 =(const float*)d_in[2];
  const float* fc2 =(const float*)d_in[3];
  const float* saw =(const float*)d_in[4];
  const float* s3d1=(const float*)d_in[5];
  const float* s3p1=(const float*)d_in[6];
  const float* s3d2=(const float*)d_in[7];
  const float* s3p2=(const float*)d_in[8];
  const float* s5d1=(const float*)d_in[9];
  const float* s5p1=(const float*)d_in[10];
  const float* s5d2=(const float*)d_in[11];
  const float* s5p2=(const float*)d_in[12];
  const float* d3dw=(const float*)d_in[13];
  const float* d3pw=(const float*)d_in[14];
  const float* d5dw=(const float*)d_in[15];
  const float* d5pw=(const float*)d_in[16];
  const int* perm=(const int*)d_in[17];
  float* out=(float*)d_out;

  char* w=(char*)d_ws;
  float* stats=(float*)w;  w+=8192;
  float* smean=(float*)w;  w+=524288;
  float* smax =(float*)w;  w+=524288;
  float* sa   =(float*)w;  w+=524288;
  float* rsum =(float*)w;  w+=16384;
  float* rmax =(float*)w;  w+=16384;
  float* att  =(float*)w;  w+=16384;
  int*   nd   =(int*)w;    w+=512;
  int*   dpos =(int*)w;    w+=512;
  size_t small_bytes=(size_t)(w-(char*)d_ws);    // 1631232
  ush* bufA=(ush*)w;
  ush* bufB=(ush*)(w+BIG);

  if(ws_size < small_bytes + 2*BIG){
    k_trivial<<<dim3(65536),dim3(256),0,stream>>>(out);
    return;
  }

  // bf16 pw weights live in the smean region (dead after k_sa). 6 x 32KB.
  ush* wb_s3p1=(ush*)smean;
  ush* wb_s3p2=wb_s3p1+16384;
  ush* wb_s5p1=wb_s3p2+16384;
  ush* wb_s5p2=wb_s5p1+16384;
  ush* wb_d3pw=wb_s5p2+16384;
  ush* wb_d5pw=wb_d3pw+16384;

  // 32-way sharded bn-stat accumulators live in smax (dead after k_sa).
  // 6 sets x 32 shards x 256 floats = 192 KB <= 512 KB.
  float* shd0=smax;            // s3p1 (sep3 mid)
  float* shd1=smax+ 8192;      // s3p2 (sep3 final)
  float* shd2=smax+16384;      // s5p1 (sep5 mid)
  float* shd3=smax+24576;      // s5p2 (sep5 final)
  float* shd4=smax+32768;      // d3pw (dil3)
  float* shd5=smax+40960;      // d5pw (dil5)

  dim3 B(256);
  dim3 Gpn(128,32);        // (p, n)
  dim3 Gpw(64,32);         // (px-tile, n) for MFMA pw
  k_zero<<<dim3(8),B,0,stream>>>(stats,2048);
  k_chan_reduce<<<dim3(16,32),B,0,stream>>>(x,smean,smax);
  k_sa<<<dim3(16,32),B,0,stream>>>(smean,smax,saw,sa);
  // smean/smax now dead -> weights + stat shards live there
  k_zero<<<dim3(192),B,0,stream>>>(smax,49152);
  k_cvt<<<dim3(64),B,0,stream>>>(s3p1,wb_s3p1);
  k_cvt<<<dim3(64),B,0,stream>>>(s3p2,wb_s3p2);
  k_cvt<<<dim3(64),B,0,stream>>>(s5p1,wb_s5p1);
  k_cvt<<<dim3(64),B,0,stream>>>(s5p2,wb_s5p2);
  k_cvt<<<dim3(64),B,0,stream>>>(d3pw,wb_d3pw);
  k_cvt<<<dim3(64),B,0,stream>>>(d5pw,wb_d5pw);
  k_rowred<<<dim3(128,32),B,0,stream>>>(x,sa,rsum,rmax);
  k_mlp<<<dim3(32),B,0,stream>>>(rsum,rmax,fc1,fc2,att);
  k_topk<<<dim3(1),dim3(128),0,stream>>>(att,perm,nd,dpos);
  k_poolstats<<<Gpn,B,0,stream>>>(x,sa,att,nd,stats);
  k_base<<<Gpn,B,0,stream>>>(x,sa,att,nd,dpos,stats,wts,out);

  // sep3: dw1 -> pw1(shd0) -> bn+relu dw2 -> pw2(shd1) -> accum
  k_dw<3,1,1><<<Gpn,B,0,stream>>>(x,nullptr,s3d1,nullptr,sa,att,nd,bufA);
  k_pw_mfma<<<Gpw,B,0,stream>>>(bufA,wb_s3p1,bufB,shd0);
  k_dw<3,1,0><<<Gpn,B,0,stream>>>(nullptr,bufB,s3d2,shd0,sa,att,nd,bufA);
  k_pw_mfma<<<Gpw,B,0,stream>>>(bufA,wb_s3p2,bufB,shd1);
  k_accum<<<dim3(16,128,32),B,0,stream>>>(bufB,nd,dpos,shd1,wts,4,out);
  // sep5
  k_dw<5,1,1><<<Gpn,B,0,stream>>>(x,nullptr,s5d1,nullptr,sa,att,nd,bufA);
  k_pw_mfma<<<Gpw,B,0,stream>>>(bufA,wb_s5p1,bufB,shd2);
  k_dw<5,1,0><<<Gpn,B,0,stream>>>(nullptr,bufB,s5d2,shd2,sa,att,nd,bufA);
  k_pw_mfma<<<Gpw,B,0,stream>>>(bufA,wb_s5p2,bufB,shd3);
  k_accum<<<dim3(16,128,32),B,0,stream>>>(bufB,nd,dpos,shd3,wts,5,out);
  // dil3
  k_dw<3,2,1><<<Gpn,B,0,stream>>>(x,nullptr,d3dw,nullptr,sa,att,nd,bufA);
  k_pw_mfma<<<Gpw,B,0,stream>>>(bufA,wb_d3pw,bufB,shd4);
  k_accum<<<dim3(16,128,32),B,0,stream>>>(bufB,nd,dpos,shd4,wts,6,out);
  // dil5
  k_dw<5,2,1><<<Gpn,B,0,stream>>>(x,nullptr,d5dw,nullptr,sa,att,nd,bufA);
  k_pw_mfma<<<Gpw,B,0,stream>>>(bufA,wb_d5pw,bufB,shd5);
  k_accum<<<dim3(16,128,32),B,0,stream>>>(bufB,nd,dpos,shd5,wts,7,out);
}

// Round 5
// 603.731 us; speedup vs baseline: 1.5089x; 1.5089x over previous
//
#include <hip/hip_runtime.h>
#include <math.h>

#define DI __device__ __forceinline__
typedef unsigned short ush;

DI float u2f(ush u){ return __uint_as_float(((unsigned int)u)<<16); }
DI ush f2u(float f){ unsigned int u=__float_as_uint(f); u += 0x7fffu + ((u>>16)&1u); return (ush)(u>>16); }

constexpr int HWc = 4096;
constexpr float RCNT = 1.f/131072.f;      // 1 / (N*H*W)
constexpr size_t BIG = 33554432ull;       // [32][128][4096] bf16 bytes

typedef __attribute__((ext_vector_type(8))) __bf16 bf8;
typedef __attribute__((ext_vector_type(4))) float  f4;

// ---------------- K0: zero a float block -----------------------------------
__global__ void k_zero(float* __restrict__ s, int n){
  int i=blockIdx.x*256+threadIdx.x;
  if(i<n) s[i]=0.f;
}

// ---------------- fallback: zero-fill output (clean diagnostic failure) ----
__global__ void k_trivial(float* __restrict__ out){
  size_t i=(size_t)blockIdx.x*256+threadIdx.x;
  if(i<16777216ull) out[i]=0.f;
}

// ---------------- K1: per-pixel channel mean/max ---------------------------
__global__ void k_chan_reduce(const float* __restrict__ x, float* __restrict__ smean, float* __restrict__ smax){
  int n = blockIdx.y;
  int px = blockIdx.x*256 + threadIdx.x;
  const float* xp = x + ((size_t)n*128)*HWc + px;
  float s=0.f, m=-INFINITY;
  #pragma unroll 8
  for(int c=0;c<128;c++){ float v=xp[(size_t)c*HWc]; s+=v; m=fmaxf(m,v); }
  smean[n*HWc+px]=s*(1.f/128.f);
  smax[n*HWc+px]=m;
}

// ---------------- K2: 7x7 conv (2->1 ch) + sigmoid -> sa -------------------
__global__ void k_sa(const float* __restrict__ smean, const float* __restrict__ smax,
                     const float* __restrict__ w, float* __restrict__ sa){
  __shared__ float wm[49], wx[49];
  int t=threadIdx.x;
  if(t<49) wm[t]=w[t];
  else if(t<98) wx[t-49]=w[t];
  __syncthreads();
  int n=blockIdx.y;
  int px=blockIdx.x*256+t;
  int r=px>>6, c=px&63;
  const float* pm  = smean + n*HWc;
  const float* pxm = smax  + n*HWc;
  float acc=0.f;
  for(int ky=0;ky<7;ky++){
    int rr=r+ky-3; if(rr<0||rr>=64) continue;
    for(int kx=0;kx<7;kx++){
      int cc=c+kx-3; if(cc<0||cc>=64) continue;
      int q=(rr<<6)+cc;
      acc += wm[ky*7+kx]*pm[q] + wx[ky*7+kx]*pxm[q];
    }
  }
  sa[n*HWc+px] = 1.f/(1.f+expf(-acc));
}

// ---------------- K3: per-(n,c) sum/max over HW of x*sa --------------------
__global__ void k_rowred(const float* __restrict__ x, const float* __restrict__ sa,
                         float* __restrict__ rsum, float* __restrict__ rmax){
  int c=blockIdx.x, n=blockIdx.y;
  const float* xp = x + ((size_t)n*128 + c)*HWc;
  const float* sp = sa + n*HWc;
  float s=0.f, m=-INFINITY;
  for(int i=threadIdx.x;i<HWc;i+=256){
    float v=xp[i]*sp[i]; s+=v; m=fmaxf(m,v);
  }
  __shared__ float ls[4], lm[4];
  for(int o=32;o>0;o>>=1){ s+=__shfl_down(s,o,64); m=fmaxf(m,__shfl_down(m,o,64)); }
  int lane=threadIdx.x&63, wv=threadIdx.x>>6;
  if(lane==0){ ls[wv]=s; lm[wv]=m; }
  __syncthreads();
  if(threadIdx.x==0){
    rsum[n*128+c]=ls[0]+ls[1]+ls[2]+ls[3];
    rmax[n*128+c]=fmaxf(fmaxf(lm[0],lm[1]),fmaxf(lm[2],lm[3]));
  }
}

// ---------------- K4a: channel-attention MLP per n -------------------------
__global__ void k_mlp(const float* __restrict__ rsum, const float* __restrict__ rmax,
                      const float* __restrict__ fc1, const float* __restrict__ fc2,
                      float* __restrict__ att){
  int n=blockIdx.x, t=threadIdx.x;
  __shared__ float zm[128], zx[128], hm[64], hx[64];
  if(t<128){ zm[t]=rsum[n*128+t]*(1.f/4096.f); zx[t]=rmax[n*128+t]; }
  __syncthreads();
  if(t<64){
    float a=0.f;
    for(int c=0;c<128;c++) a+=fc1[t*128+c]*zm[c];
    hm[t]=fmaxf(a,0.f);
  } else if(t<128){
    int j=t-64; float a=0.f;
    for(int c=0;c<128;c++) a+=fc1[j*128+c]*zx[c];
    hx[j]=fmaxf(a,0.f);
  }
  __syncthreads();
  if(t<128){
    float a=0.f,b=0.f;
    for(int j=0;j<64;j++){ float wv=fc2[t*64+j]; a+=wv*hm[j]; b+=wv*hx[j]; }
    att[n*128+t]=1.f/(1.f+expf(-(a+b)));
  }
}

// ---------------- K4b: slist, top-96, num_dict, last-occurrence map --------
__global__ void k_topk(const float* __restrict__ att, const int* __restrict__ perm,
                       int* __restrict__ nd_out, int* __restrict__ dst_pos){
  __shared__ float sl[128];
  __shared__ int nd[128];
  int t=threadIdx.x;          // 128 threads
  float s=0.f;
  for(int n=0;n<32;n++) s+=att[n*128+t];
  sl[t]=s;
  nd[t]=t;
  __syncthreads();
  float v=sl[t]; int r=0;
  for(int c=0;c<128;c++){ float u=sl[c]; r += ((u>v) || (u==v && c<t)) ? 1 : 0; }
  if(r<96) nd[r]=t;
  __syncthreads();
  if(t<32) nd[96+t]=perm[t]&127;
  __syncthreads();
  nd_out[t]=nd[t]&127;
  int pos=-1;
  for(int p=0;p<128;p++) if((nd[p]&127)==t) pos=p;
  dst_pos[t]=pos;
}

// ---------------- zero the halo pad columns of a padded LDS plane ----------
template<int R,int S>
DI void stage_pads(float* __restrict__ Pl, int t){
  if(t<64){
    #pragma unroll
    for(int j=0;j<R;j++) Pl[t*S+j]=0.f;
    #pragma unroll
    for(int j=64+R;j<S;j++) Pl[t*S+j]=0.f;
  }
}

// ---------------- K6: bn stats of max_pool3(xt), avg_pool3(xt) -------------
// Register-tiled: thread owns 16-px row strip; 3 row-segment b128 load sets.
__global__ __launch_bounds__(256) void k_poolstats(const float* __restrict__ x,
    const float* __restrict__ sa, const float* __restrict__ att,
    const int* __restrict__ nd, float* __restrict__ stats){
  constexpr int S=68;
  __shared__ float Pl[64*S];
  int p=blockIdx.x, n=blockIdx.y, t=threadIdx.x;
  int chs=nd[p]&127;
  float a=att[n*128+chs];
  const float* xp = x + ((size_t)n*128+chs)*HWc;
  const float* sp = sa + n*HWc;
  #pragma unroll
  for(int k=0;k<16;k++){
    int px=t+k*256;
    Pl[(px>>6)*S + 1 + (px&63)] = xp[px]*sp[px]*a;
  }
  stage_pads<1,S>(Pl,t);
  __syncthreads();
  int r=t>>2, c0=(t&3)*16;
  float s[16], m[16];
  #pragma unroll
  for(int i=0;i<16;i++){ s[i]=0.f; m[i]=-INFINITY; }
  int rin=0;
  #pragma unroll
  for(int ky=-1;ky<=1;ky++){
    int rr=r+ky;
    if(rr<0||rr>=64) continue;
    rin++;
    float row[20];
    #pragma unroll
    for(int j=0;j<5;j++) *(float4*)&row[4*j] = *(const float4*)&Pl[rr*S + c0 + 4*j];
    // row[j] holds data col (c0-1+j); pads are zero.
    float e0  = (c0==0)  ? -INFINITY : row[0];
    float e17 = (c0==48) ? -INFINITY : row[17];
    #pragma unroll
    for(int i=0;i<16;i++){
      float lf = (i==0)  ? e0  : row[i];
      float rg = (i==15) ? e17 : row[i+2];
      s[i] += row[i]+row[i+1]+row[i+2];
      m[i] = fmaxf(m[i], fmaxf(lf, fmaxf(row[i+1], rg)));
    }
  }
  float sm=0,qm=0,sv=0,qv=0;
  #pragma unroll
  for(int i=0;i<16;i++){
    int c=c0+i;
    float cnt=(float)(rin*(3-(c==0)-(c==63)));
    float ap=s[i]/cnt, mp=m[i];
    sm+=mp; qm+=mp*mp; sv+=ap; qv+=ap*ap;
  }
  for(int o=32;o>0;o>>=1){
    sm+=__shfl_down(sm,o,64); qm+=__shfl_down(qm,o,64);
    sv+=__shfl_down(sv,o,64); qv+=__shfl_down(qv,o,64);
  }
  __shared__ float l[4][4];
  int lane=t&63, wv=t>>6;
  if(lane==0){ l[wv][0]=sm; l[wv][1]=qm; l[wv][2]=sv; l[wv][3]=qv; }
  __syncthreads();
  if(t==0){
    atomicAdd(&stats[p],     l[0][0]+l[1][0]+l[2][0]+l[3][0]);
    atomicAdd(&stats[128+p], l[0][1]+l[1][1]+l[2][1]+l[3][1]);
    atomicAdd(&stats[256+p], l[0][2]+l[1][2]+l[2][2]+l[3][2]);
    atomicAdd(&stats[384+p], l[0][3]+l[1][3]+l[2][3]+l[3][3]);
  }
}

// ---------------- K8a: base of output (register-tiled pool3) ---------------
__global__ __launch_bounds__(256) void k_base(const float* __restrict__ x,
    const float* __restrict__ sa, const float* __restrict__ att,
    const int* __restrict__ nd, const int* __restrict__ dpos,
    const float* __restrict__ stats, const float* __restrict__ wts,
    float* __restrict__ out){
  constexpr int S=68;
  __shared__ float Pl[64*S];
  int ch=blockIdx.x, n=blockIdx.y, t=threadIdx.x;
  int p=dpos[ch];                      // block-uniform branch
  const float* sp = sa + n*HWc;
  if(p<0){
    float a=att[n*128+ch];
    const float* xp = x + ((size_t)n*128+ch)*HWc;
    float* op = out + ((size_t)n*128+ch)*HWc;
    for(int px=t;px<HWc;px+=256) op[px]=xp[px]*sp[px]*a;
    return;
  }
  p&=127;
  int chs=nd[p]&127;
  float a=att[n*128+chs];
  const float* xp = x + ((size_t)n*128+chs)*HWc;
  #pragma unroll
  for(int k=0;k<16;k++){
    int px=t+k*256;
    Pl[(px>>6)*S + 1 + (px&63)] = xp[px]*sp[px]*a;
  }
  stage_pads<1,S>(Pl,t);
  __syncthreads();
  float w1=wts[1],w2=wts[2],w3=wts[3];
  float m0,r0v,m1,r1v;
  { float su=stats[p],     sq=stats[128+p]; float mean=su*RCNT,var=sq*RCNT-mean*mean; m0=mean; r0v=rsqrtf(var+1e-5f); }
  { float su=stats[256+p], sq=stats[384+p]; float mean=su*RCNT,var=sq*RCNT-mean*mean; m1=mean; r1v=rsqrtf(var+1e-5f); }
  int r=t>>2, c0=(t&3)*16;
  float s[16], m[16], crow[16];
  #pragma unroll
  for(int i=0;i<16;i++){ s[i]=0.f; m[i]=-INFINITY; }
  int rin=0;
  #pragma unroll
  for(int ky=-1;ky<=1;ky++){
    int rr=r+ky;
    if(rr<0||rr>=64) continue;
    rin++;
    float row[20];
    #pragma unroll
    for(int j=0;j<5;j++) *(float4*)&row[4*j] = *(const float4*)&Pl[rr*S + c0 + 4*j];
    if(ky==0){
      #pragma unroll
      for(int i=0;i<16;i++) crow[i]=row[i+1];
    }
    float e0  = (c0==0)  ? -INFINITY : row[0];
    float e17 = (c0==48) ? -INFINITY : row[17];
    #pragma unroll
    for(int i=0;i<16;i++){
      float lf = (i==0)  ? e0  : row[i];
      float rg = (i==15) ? e17 : row[i+2];
      s[i] += row[i]+row[i+1]+row[i+2];
      m[i] = fmaxf(m[i], fmaxf(lf, fmaxf(row[i+1], rg)));
    }
  }
  float* op = out + ((size_t)n*128+ch)*HWc + r*64 + c0;
  float v[16];
  #pragma unroll
  for(int i=0;i<16;i++){
    int c=c0+i;
    float cnt=(float)(rin*(3-(c==0)-(c==63)));
    float ap=s[i]/cnt;
    v[i] = w3*crow[i] + w1*(m[i]-m0)*r0v + w2*(ap-m1)*r1v;
  }
  #pragma unroll
  for(int q=0;q<4;q++) *(float4*)(op+4*q) = *(float4*)&v[4*q];
}

// ---------------- K_dw: depthwise conv on one (n,p) plane ------------------
// Register-tiled: thread owns 16-px row strip (r=t>>2, c0=(t&3)*16).
// SX=1: input = relu(x[nd[p]]*sa*att). SX=0: input = relu(bn(bf16 buf)) with
// finalized mean/rstd from fin[p], fin[128+p].
// IN-PLACE SAFE (bufsrc==outb): the whole (n,p) plane is staged into LDS
// (reads complete before the barrier) before any global write. No __restrict__
// on the aliased pointers.
template<int KS,int DIL,int SX>
__global__ __launch_bounds__(256) void k_dw(const float* __restrict__ xsrc,
    const ush* bufsrc, const float* __restrict__ dww,
    const float* __restrict__ fin, const float* __restrict__ sa,
    const float* __restrict__ att, const int* __restrict__ nd,
    ush* outb){
  constexpr int R=(KS/2)*DIL;          // halo reach: 1,2,2,4
  constexpr int S=(R==4)?76:68;        // stride = 4 mod 32, 16B-aligned
  constexpr int L=16+2*R;              // row floats needed
  constexpr int NL=(L+3)/4;            // float4 loads per row (5 or 6)
  __shared__ float Pl[64*S];
  int p=blockIdx.x, n=blockIdx.y, t=threadIdx.x;
  const float* sp = sa + n*HWc;
  if constexpr (SX){
    int ch=nd[p]&127;
    float a=att[n*128+ch];
    const float* xp = xsrc + ((size_t)n*128+ch)*HWc;
    #pragma unroll
    for(int k=0;k<16;k++){
      int px=t+k*256;
      Pl[(px>>6)*S + R + (px&63)] = fmaxf(xp[px]*sp[px]*a,0.f);
    }
  } else {
    float mean=fin[p], rstd=fin[128+p];
    const ush* bp = bufsrc + ((size_t)n*128+p)*HWc;
    #pragma unroll
    for(int k=0;k<16;k++){
      int px=t+k*256;
      Pl[(px>>6)*S + R + (px&63)] = fmaxf((u2f(bp[px])-mean)*rstd,0.f);
    }
  }
  stage_pads<R,S>(Pl,t);
  __syncthreads();
  float wk[KS*KS];
  #pragma unroll
  for(int i=0;i<KS*KS;i++) wk[i]=dww[p*KS*KS+i];
  int r=t>>2, c0=(t&3)*16;
  float acc[16];
  #pragma unroll
  for(int i=0;i<16;i++) acc[i]=0.f;
  #pragma unroll
  for(int ky=0;ky<KS;ky++){
    int rr=r+(ky-KS/2)*DIL;
    if(rr<0||rr>=64) continue;
    float row[NL*4];
    #pragma unroll
    for(int j=0;j<NL;j++) *(float4*)&row[4*j] = *(const float4*)&Pl[rr*S + c0 + 4*j];
    #pragma unroll
    for(int kx=0;kx<KS;kx++){
      float wv=wk[ky*KS+kx];
      #pragma unroll
      for(int i=0;i<16;i++) acc[i]+=wv*row[R + i + (kx-KS/2)*DIL];
    }
  }
  ush* op = outb + ((size_t)n*128+p)*HWc + r*64 + c0;
  #pragma unroll
  for(int q=0;q<4;q++){
    ushort4 vv;
    vv.x=f2u(acc[4*q+0]); vv.y=f2u(acc[4*q+1]);
    vv.z=f2u(acc[4*q+2]); vv.w=f2u(acc[4*q+3]);
    *(ushort4*)(op+4*q)=vv;
  }
}

// ---------------- K_wcvt: f32 -> bf16 weight convert (16384 elems) ---------
__global__ void k_cvt(const float* __restrict__ src, ush* __restrict__ dst){
  int i=blockIdx.x*256+threadIdx.x;
  dst[i]=f2u(src[i]);
}

// ---------------- K_statfin: fold 32 shards -> mean/rstd -------------------
__global__ void k_statfin(const float* __restrict__ shd, float* __restrict__ fin){
  int t=threadIdx.x;                   // 128
  if(t<128){
    float su=0.f, sq=0.f;
    #pragma unroll
    for(int j=0;j<32;j++){ su+=shd[j*256+t]; sq+=shd[j*256+128+t]; }
    float mean=su*RCNT, var=sq*RCNT-mean*mean;
    fin[t]=mean;
    fin[128+t]=rsqrtf(var+1e-5f);
  }
}

// ---------------- K_pw_mfma: pointwise 128->128 MFMA GEMM + bn stats -------
// D[co][px] = sum_ci W[co][ci] * dwin[ci][px], bf16 in, f32 acc, bf16 out.
// Block: 256 thr = 4 waves; tile M=128(co) x N=64(px), K=128 (4 steps of 32).
// B staged in LDS TRANSPOSED: Bt[px][ci] (pad +4) -> plain 8B k-contiguous
// fragment reads (m92/m97-verified pattern). A-frags from global bf16.
// bn-stats partials go to 32-way SHARDED accumulators (Guideline 12).
// IN-PLACE SAFE (dwin==outb): block reads only its own 64-px window, fully
// staged to LDS before the barrier; writes same window after. No __restrict__
// on the aliased pointers.
__global__ __launch_bounds__(256) void k_pw_mfma(const ush* dwin,
    const ush* __restrict__ wt, ush* outb, float* __restrict__ shad){
  __shared__ ush Bt[64][132];          // 16.9 KiB, row stride 264 B
  int t=threadIdx.x, n=blockIdx.y;
  int px0b = blockIdx.x*64;

  const ush* dp = dwin + ((size_t)n*128)*HWc + px0b;
  // stage + transpose: thread handles ci pair (2*c2, 2*c2+1) x 4 px
  #pragma unroll
  for(int k=0;k<4;k++){
    int e = t + k*256;                 // [0,1024)
    int c2 = e>>4;                     // ci pair 0..63
    int p4 = (e&15)*4;                 // px 0..60 step 4
    const ush* g0 = dp + (size_t)(2*c2)*HWc + p4;
    ushort4 va = *(const ushort4*)g0;
    ushort4 vb = *(const ushort4*)(g0 + HWc);
    *(unsigned int*)&Bt[p4+0][2*c2] = (unsigned int)va.x | ((unsigned int)vb.x<<16);
    *(unsigned int*)&Bt[p4+1][2*c2] = (unsigned int)va.y | ((unsigned int)vb.y<<16);
    *(unsigned int*)&Bt[p4+2][2*c2] = (unsigned int)va.z | ((unsigned int)vb.z<<16);
    *(unsigned int*)&Bt[p4+3][2*c2] = (unsigned int)va.w | ((unsigned int)vb.w<<16);
  }

  int lane=t&63, wv=t>>6;
  int co0=(wv>>1)*64, pxw=(wv&1)*32;   // wave tile: 64 co x 32 px
  int g=lane>>4, sl=lane&15;
  // A fragments (verified layout): row(M)=co0+mt*16+sl, k=kt*32+g*8+j (j=0..7)
  int arow = co0 + sl;
  int acg  = g*8;
  bf8 a[4][4];
  #pragma unroll
  for(int mt=0;mt<4;mt++)
    #pragma unroll
    for(int kt=0;kt<4;kt++)
      a[mt][kt] = *(const bf8*)(wt + (size_t)(arow+mt*16)*128 + kt*32 + acg);

  f4 acc[4][2] = {};
  __syncthreads();

  #pragma unroll
  for(int nt=0;nt<2;nt++){
    int pxl = pxw + nt*16 + sl;        // col(N)=lane&15 within 16-px group
    bf8 b[4];
    #pragma unroll
    for(int kt=0;kt<4;kt++){
      union { uint2 h[2]; bf8 v; } u;
      const ush* bp = &Bt[pxl][kt*32 + acg];
      u.h[0] = *(const uint2*)bp;      // 8B-aligned (264*px + 64kt + 16g)
      u.h[1] = *(const uint2*)(bp+4);
      b[kt] = u.v;
    }
    #pragma unroll
    for(int kt=0;kt<4;kt++)
      #pragma unroll
      for(int mt=0;mt<4;mt++)
        acc[mt][nt] = __builtin_amdgcn_mfma_f32_16x16x32_bf16(a[mt][kt], b[kt], acc[mt][nt], 0,0,0);
  }

  // Epilogue: D layout col(px)=lane&15, row(co)=(lane>>4)*4+r. Store bf16 +
  // fused bn stats (sum, sumsq per co) via 16-lane reduce + sharded atomics.
  float* sh = shad + (((blockIdx.x + blockIdx.y)&31)*256);
  #pragma unroll
  for(int mt=0;mt<4;mt++){
    #pragma unroll
    for(int r=0;r<4;r++){
      int co = co0 + mt*16 + g*4 + r;
      float v0=acc[mt][0][r], v1=acc[mt][1][r];
      ush* ob = outb + ((size_t)n*128+co)*HWc + px0b + pxw;
      ob[sl]      = f2u(v0);
      ob[16+sl]   = f2u(v1);
      float s1 = v0+v1, s2 = v0*v0+v1*v1;
      #pragma unroll
      for(int o=1;o<16;o<<=1){ s1+=__shfl_xor(s1,o,64); s2+=__shfl_xor(s2,o,64); }
      if(sl==0){ atomicAdd(&sh[co],s1); atomicAdd(&sh[128+co],s2); }
    }
  }
}

// ---------------- K8b: fused dual-branch accumulate ------------------------
// out += wA*bn(brA) + wB*bn(brB) for winning positions. 8 px/thread,
// uint4 bf16 loads + float4 RMW (G13). mean/rstd from finalized tables.
__global__ __launch_bounds__(256) void k_accum2(const ush* __restrict__ brA,
    const ush* __restrict__ brB, const int* __restrict__ nd,
    const int* __restrict__ dpos, const float* __restrict__ finA,
    const float* __restrict__ finB, const float* __restrict__ wts,
    int wiA, int wiB, float* __restrict__ out){
  int n=blockIdx.z, p=blockIdx.y;
  int ch=nd[p]&127;
  if(dpos[ch]!=p) return;
  int px=(blockIdx.x*256+threadIdx.x)*8;
  float mA=finA[p], rA=finA[128+p];
  float mB=finB[p], rB=finB[128+p];
  float wA=wts[wiA], wB=wts[wiB];
  size_t bidx=((size_t)n*128+p)*HWc+px;
  size_t oidx=((size_t)n*128+ch)*HWc+px;
  uint4 va=*(const uint4*)(brA+bidx);
  uint4 vb=*(const uint4*)(brB+bidx);
  unsigned int wa[4]={va.x,va.y,va.z,va.w};
  unsigned int wb[4]={vb.x,vb.y,vb.z,vb.w};
  float4 o0=*(const float4*)(out+oidx);
  float4 o1=*(const float4*)(out+oidx+4);
  float o[8]={o0.x,o0.y,o0.z,o0.w,o1.x,o1.y,o1.z,o1.w};
  #pragma unroll
  for(int j=0;j<4;j++){
    float a0=u2f((ush)(wa[j]&0xffff)), a1=u2f((ush)(wa[j]>>16));
    float b0=u2f((ush)(wb[j]&0xffff)), b1=u2f((ush)(wb[j]>>16));
    o[2*j]   += wA*(a0-mA)*rA + wB*(b0-mB)*rB;
    o[2*j+1] += wA*(a1-mA)*rA + wB*(b1-mB)*rB;
  }
  *(float4*)(out+oidx)   = make_float4(o[0],o[1],o[2],o[3]);
  *(float4*)(out+oidx+4) = make_float4(o[4],o[5],o[6],o[7]);
}

extern "C" void kernel_launch(void* const* d_in, const int* in_sizes, int n_in,
                              void* d_out, int out_size, void* d_ws, size_t ws_size,
                              hipStream_t stream){
  (void)in_sizes; (void)n_in; (void)out_size;
  const float* x   =(const float*)d_in[0];
  const float* wts =(const float*)d_in[1];
  const float* fc1 =(const float*)d_in[2];
  const float* fc2 =(const float*)d_in[3];
  const float* saw =(const float*)d_in[4];
  const float* s3d1=(const float*)d_in[5];
  const float* s3p1=(const float*)d_in[6];
  const float* s3d2=(const float*)d_in[7];
  const float* s3p2=(const float*)d_in[8];
  const float* s5d1=(const float*)d_in[9];
  const float* s5p1=(const float*)d_in[10];
  const float* s5d2=(const float*)d_in[11];
  const float* s5p2=(const float*)d_in[12];
  const float* d3dw=(const float*)d_in[13];
  const float* d3pw=(const float*)d_in[14];
  const float* d5dw=(const float*)d_in[15];
  const float* d5pw=(const float*)d_in[16];
  const int* perm=(const int*)d_in[17];
  float* out=(float*)d_out;

  char* w=(char*)d_ws;
  float* stats=(float*)w;  w+=8192;
  float* smean=(float*)w;  w+=524288;
  float* smax =(float*)w;  w+=524288;
  float* sa   =(float*)w;  w+=524288;
  float* rsum =(float*)w;  w+=16384;
  float* rmax =(float*)w;  w+=16384;
  float* att  =(float*)w;  w+=16384;
  int*   nd   =(int*)w;    w+=512;
  int*   dpos =(int*)w;    w+=512;
  size_t small_bytes=(size_t)(w-(char*)d_ws);    // 1631232
  ush* bufA=(ush*)w;
  ush* bufB=(ush*)(w+BIG);

  if(ws_size < small_bytes + 2*BIG){
    k_trivial<<<dim3(65536),dim3(256),0,stream>>>(out);
    return;
  }

  // bf16 pw weights live in the smean region (dead after k_sa). 6 x 32KB.
  ush* wb_s3p1=(ush*)smean;
  ush* wb_s3p2=wb_s3p1+16384;
  ush* wb_s5p1=wb_s3p2+16384;
  ush* wb_s5p2=wb_s5p1+16384;
  ush* wb_d3pw=wb_s5p2+16384;
  ush* wb_d5pw=wb_d3pw+16384;

  // 32-way sharded bn-stat accumulators live in smax (dead after k_sa).
  float* shd0=smax;            // s3p1 (sep3 mid)
  float* shd1=smax+ 8192;      // s3p2 (sep3 final)
  float* shd2=smax+16384;      // s5p1 (sep5 mid)
  float* shd3=smax+24576;      // s5p2 (sep5 final)
  float* shd4=smax+32768;      // d3pw (dil3)
  float* shd5=smax+40960;      // d5pw (dil5)

  // finalized mean/rstd tables in the stats block (sets 2..7 free)
  float* fin0=stats+ 512;
  float* fin1=stats+ 768;
  float* fin2=stats+1024;
  float* fin3=stats+1280;
  float* fin4=stats+1536;
  float* fin5=stats+1792;

  dim3 B(256);
  dim3 Gpn(128,32);        // (p, n)
  dim3 Gpw(64,32);         // (px-tile, n) for MFMA pw
  dim3 Gac(2,128,32);      // (px-block, p, n) for fused accum
  k_zero<<<dim3(8),B,0,stream>>>(stats,2048);
  k_chan_reduce<<<dim3(16,32),B,0,stream>>>(x,smean,smax);
  k_sa<<<dim3(16,32),B,0,stream>>>(smean,smax,saw,sa);
  // smean/smax now dead -> weights + stat shards live there
  k_zero<<<dim3(192),B,0,stream>>>(smax,49152);
  k_cvt<<<dim3(64),B,0,stream>>>(s3p1,wb_s3p1);
  k_cvt<<<dim3(64),B,0,stream>>>(s3p2,wb_s3p2);
  k_cvt<<<dim3(64),B,0,stream>>>(s5p1,wb_s5p1);
  k_cvt<<<dim3(64),B,0,stream>>>(s5p2,wb_s5p2);
  k_cvt<<<dim3(64),B,0,stream>>>(d3pw,wb_d3pw);
  k_cvt<<<dim3(64),B,0,stream>>>(d5pw,wb_d5pw);
  k_rowred<<<dim3(128,32),B,0,stream>>>(x,sa,rsum,rmax);
  k_mlp<<<dim3(32),B,0,stream>>>(rsum,rmax,fc1,fc2,att);
  k_topk<<<dim3(1),dim3(128),0,stream>>>(att,perm,nd,dpos);
  k_poolstats<<<Gpn,B,0,stream>>>(x,sa,att,nd,stats);
  k_base<<<Gpn,B,0,stream>>>(x,sa,att,nd,dpos,stats,wts,out);

  // sep3 entirely in bufA (dw and pw are in-place safe)
  k_dw<3,1,1><<<Gpn,B,0,stream>>>(x,nullptr,s3d1,nullptr,sa,att,nd,bufA);
  k_pw_mfma<<<Gpw,B,0,stream>>>(bufA,wb_s3p1,bufA,shd0);
  k_statfin<<<dim3(1),dim3(128),0,stream>>>(shd0,fin0);
  k_dw<3,1,0><<<Gpn,B,0,stream>>>(nullptr,bufA,s3d2,fin0,sa,att,nd,bufA);
  k_pw_mfma<<<Gpw,B,0,stream>>>(bufA,wb_s3p2,bufA,shd1);
  k_statfin<<<dim3(1),dim3(128),0,stream>>>(shd1,fin1);
  // sep5 entirely in bufB
  k_dw<5,1,1><<<Gpn,B,0,stream>>>(x,nullptr,s5d1,nullptr,sa,att,nd,bufB);
  k_pw_mfma<<<Gpw,B,0,stream>>>(bufB,wb_s5p1,bufB,shd2);
  k_statfin<<<dim3(1),dim3(128),0,stream>>>(shd2,fin2);
  k_dw<5,1,0><<<Gpn,B,0,stream>>>(nullptr,bufB,s5d2,fin2,sa,att,nd,bufB);
  k_pw_mfma<<<Gpw,B,0,stream>>>(bufB,wb_s5p2,bufB,shd3);
  k_statfin<<<dim3(1),dim3(128),0,stream>>>(shd3,fin3);
  // one fused RMW for sep3+sep5
  k_accum2<<<Gac,B,0,stream>>>(bufA,bufB,nd,dpos,fin1,fin3,wts,4,5,out);
  // dil3 in bufA, dil5 in bufB
  k_dw<3,2,1><<<Gpn,B,0,stream>>>(x,nullptr,d3dw,nullptr,sa,att,nd,bufA);
  k_pw_mfma<<<Gpw,B,0,stream>>>(bufA,wb_d3pw,bufA,shd4);
  k_statfin<<<dim3(1),dim3(128),0,stream>>>(shd4,fin4);
  k_dw<5,2,1><<<Gpn,B,0,stream>>>(x,nullptr,d5dw,nullptr,sa,att,nd,bufB);
  k_pw_mfma<<<Gpw,B,0,stream>>>(bufB,wb_d5pw,bufB,shd5);
  k_statfin<<<dim3(1),dim3(128),0,stream>>>(shd5,fin5);
  // one fused RMW for dil3+dil5
  k_accum2<<<Gac,B,0,stream>>>(bufA,bufB,nd,dpos,fin4,fin5,wts,6,7,out);
}

// Round 7
// 479.549 us; speedup vs baseline: 1.8996x; 1.2590x over previous
//
#include <hip/hip_runtime.h>
#include <math.h>

#define DI __device__ __forceinline__
typedef unsigned short ush;

DI float u2f(ush u){ return __uint_as_float(((unsigned int)u)<<16); }
DI ush f2u(float f){ unsigned int u=__float_as_uint(f); u += 0x7fffu + ((u>>16)&1u); return (ush)(u>>16); }

constexpr int HWc = 4096;
constexpr float RCNT = 1.f/131072.f;      // 1 / (N*H*W)
constexpr size_t BIG = 33554432ull;       // [32][128][4096] bf16 bytes

typedef __attribute__((ext_vector_type(8))) __bf16 bf8;
typedef __attribute__((ext_vector_type(4))) float  f4;

DI void unp8(uint4 q, float* o){
  o[0]=u2f((ush)(q.x&0xffff)); o[1]=u2f((ush)(q.x>>16));
  o[2]=u2f((ush)(q.y&0xffff)); o[3]=u2f((ush)(q.y>>16));
  o[4]=u2f((ush)(q.z&0xffff)); o[5]=u2f((ush)(q.z>>16));
  o[6]=u2f((ush)(q.w&0xffff)); o[7]=u2f((ush)(q.w>>16));
}
DI uint4 pk8(const ush* u){
  uint4 q;
  q.x=(unsigned)u[0]|((unsigned)u[1]<<16); q.y=(unsigned)u[2]|((unsigned)u[3]<<16);
  q.z=(unsigned)u[4]|((unsigned)u[5]<<16); q.w=(unsigned)u[6]|((unsigned)u[7]<<16);
  return q;
}

// ---------------- K0: zero stats + stat shards in one pass -----------------
__global__ void k_zero2(float* __restrict__ a, float* __restrict__ b){
  int i=blockIdx.x*256+threadIdx.x;
  if(i<2048) a[i]=0.f;
  else if(i<2048+49152) b[i-2048]=0.f;
}

// ---------------- fallback: zero-fill output (clean diagnostic failure) ----
__global__ void k_trivial(float* __restrict__ out){
  size_t i=(size_t)blockIdx.x*256+threadIdx.x;
  if(i<16777216ull) out[i]=0.f;
}

// ---------------- K1: per-pixel channel mean/max ---------------------------
__global__ void k_chan_reduce(const float* __restrict__ x, float* __restrict__ smean, float* __restrict__ smax){
  int n = blockIdx.y;
  int px = blockIdx.x*256 + threadIdx.x;
  const float* xp = x + ((size_t)n*128)*HWc + px;
  float s=0.f, m=-INFINITY;
  #pragma unroll 8
  for(int c=0;c<128;c++){ float v=xp[(size_t)c*HWc]; s+=v; m=fmaxf(m,v); }
  smean[n*HWc+px]=s*(1.f/128.f);
  smax[n*HWc+px]=m;
}

// ---------------- K2: 7x7 conv (2->1 ch) + sigmoid -> sa -------------------
__global__ void k_sa(const float* __restrict__ smean, const float* __restrict__ smax,
                     const float* __restrict__ w, float* __restrict__ sa){
  __shared__ float wm[49], wx[49];
  int t=threadIdx.x;
  if(t<49) wm[t]=w[t];
  else if(t<98) wx[t-49]=w[t];
  __syncthreads();
  int n=blockIdx.y;
  int px=blockIdx.x*256+t;
  int r=px>>6, c=px&63;
  const float* pm  = smean + n*HWc;
  const float* pxm = smax  + n*HWc;
  float acc=0.f;
  for(int ky=0;ky<7;ky++){
    int rr=r+ky-3; if(rr<0||rr>=64) continue;
    for(int kx=0;kx<7;kx++){
      int cc=c+kx-3; if(cc<0||cc>=64) continue;
      int q=(rr<<6)+cc;
      acc += wm[ky*7+kx]*pm[q] + wx[ky*7+kx]*pxm[q];
    }
  }
  sa[n*HWc+px] = 1.f/(1.f+expf(-acc));
}

// ---------------- K3: per-(n,c) sum/max over HW of x*sa --------------------
__global__ void k_rowred(const float* __restrict__ x, const float* __restrict__ sa,
                         float* __restrict__ rsum, float* __restrict__ rmax){
  int c=blockIdx.x, n=blockIdx.y;
  const float* xp = x + ((size_t)n*128 + c)*HWc;
  const float* sp = sa + n*HWc;
  float s=0.f, m=-INFINITY;
  for(int i=threadIdx.x;i<HWc;i+=256){
    float v=xp[i]*sp[i]; s+=v; m=fmaxf(m,v);
  }
  __shared__ float ls[4], lm[4];
  for(int o=32;o>0;o>>=1){ s+=__shfl_down(s,o,64); m=fmaxf(m,__shfl_down(m,o,64)); }
  int lane=threadIdx.x&63, wv=threadIdx.x>>6;
  if(lane==0){ ls[wv]=s; lm[wv]=m; }
  __syncthreads();
  if(threadIdx.x==0){
    rsum[n*128+c]=ls[0]+ls[1]+ls[2]+ls[3];
    rmax[n*128+c]=fmaxf(fmaxf(lm[0],lm[1]),fmaxf(lm[2],lm[3]));
  }
}

// ---------------- K4a: channel-attention MLP per n -------------------------
__global__ void k_mlp(const float* __restrict__ rsum, const float* __restrict__ rmax,
                      const float* __restrict__ fc1, const float* __restrict__ fc2,
                      float* __restrict__ att){
  int n=blockIdx.x, t=threadIdx.x;
  __shared__ float zm[128], zx[128], hm[64], hx[64];
  if(t<128){ zm[t]=rsum[n*128+t]*(1.f/4096.f); zx[t]=rmax[n*128+t]; }
  __syncthreads();
  if(t<64){
    float a=0.f;
    for(int c=0;c<128;c++) a+=fc1[t*128+c]*zm[c];
    hm[t]=fmaxf(a,0.f);
  } else if(t<128){
    int j=t-64; float a=0.f;
    for(int c=0;c<128;c++) a+=fc1[j*128+c]*zx[c];
    hx[j]=fmaxf(a,0.f);
  }
  __syncthreads();
  if(t<128){
    float a=0.f,b=0.f;
    for(int j=0;j<64;j++){ float wv=fc2[t*64+j]; a+=wv*hm[j]; b+=wv*hx[j]; }
    att[n*128+t]=1.f/(1.f+expf(-(a+b)));
  }
}

// ---------------- K4b: slist, top-96, num_dict, last-occurrence map --------
__global__ void k_topk(const float* __restrict__ att, const int* __restrict__ perm,
                       int* __restrict__ nd_out, int* __restrict__ dst_pos){
  __shared__ float sl[128];
  __shared__ int nd[128];
  int t=threadIdx.x;          // 128 threads
  float s=0.f;
  for(int n=0;n<32;n++) s+=att[n*128+t];
  sl[t]=s;
  nd[t]=t;
  __syncthreads();
  float v=sl[t]; int r=0;
  for(int c=0;c<128;c++){ float u=sl[c]; r += ((u>v) || (u==v && c<t)) ? 1 : 0; }
  if(r<96) nd[r]=t;
  __syncthreads();
  if(t<32) nd[96+t]=perm[t]&127;
  __syncthreads();
  nd_out[t]=nd[t]&127;
  int pos=-1;
  for(int p=0;p<128;p++) if((nd[p]&127)==t) pos=p;
  dst_pos[t]=pos;
}

// ---------------- zero the halo pad columns of a padded LDS plane ----------
template<int R,int S>
DI void stage_pads(float* __restrict__ Pl, int t){
  if(t<64){
    #pragma unroll
    for(int j=0;j<R;j++) Pl[t*S+j]=0.f;
    #pragma unroll
    for(int j=64+R;j<S;j++) Pl[t*S+j]=0.f;
  }
}

// ---------------- K_cvt6: 6x f32->bf16 weight convert in one launch --------
__global__ void k_cvt6(const float* __restrict__ a,const float* __restrict__ b,
    const float* __restrict__ c,const float* __restrict__ d,
    const float* __restrict__ e,const float* __restrict__ f,
    ush* __restrict__ wb){
  int z=blockIdx.y;
  const float* src = z==0?a:z==1?b:z==2?c:z==3?d:z==4?e:f;
  int i=blockIdx.x*256+threadIdx.x;
  wb[z*16384+i]=f2u(src[i]);
}

// ---------------- K_xtps: xt = bf16(x[nd[p]]*sa*att) + fused poolstats -----
// Writes the gathered xt plane to bufX AND computes bn stats of
// max_pool3 / avg_pool3 from the same LDS-staged (bf16-rounded) plane.
__global__ __launch_bounds__(256) void k_xtps(const float* __restrict__ x,
    const float* __restrict__ sa, const float* __restrict__ att,
    const int* __restrict__ nd, ush* __restrict__ bufX, float* __restrict__ stats){
  constexpr int S=68;
  __shared__ float Pl[64*S];
  int p=blockIdx.x, n=blockIdx.y, t=threadIdx.x;
  int ch=nd[p]&127;
  float a=att[n*128+ch];
  const float* xp=x+((size_t)n*128+ch)*HWc;
  const float* sp=sa+n*HWc;
  int px0=t*16;
  ush u[16];
  #pragma unroll
  for(int j=0;j<4;j++){
    float4 xv=*(const float4*)(xp+px0+4*j);
    float4 sv=*(const float4*)(sp+px0+4*j);
    u[4*j+0]=f2u(xv.x*sv.x*a); u[4*j+1]=f2u(xv.y*sv.y*a);
    u[4*j+2]=f2u(xv.z*sv.z*a); u[4*j+3]=f2u(xv.w*sv.w*a);
  }
  ush* bo=bufX+((size_t)n*128+p)*HWc+px0;
  *(uint4*)bo   = pk8(u);
  *(uint4*)(bo+8)= pk8(u+8);
  float* dst=&Pl[(px0>>6)*S + 1 + (px0&63)];
  #pragma unroll
  for(int i=0;i<16;i++) dst[i]=u2f(u[i]);
  stage_pads<1,S>(Pl,t);
  __syncthreads();
  int r=t>>2, c0=(t&3)*16;
  float s[16], m[16];
  #pragma unroll
  for(int i=0;i<16;i++){ s[i]=0.f; m[i]=-INFINITY; }
  int rin=0;
  #pragma unroll
  for(int ky=-1;ky<=1;ky++){
    int rr=r+ky;
    if(rr<0||rr>=64) continue;
    rin++;
    float row[20];
    #pragma unroll
    for(int j=0;j<5;j++) *(float4*)&row[4*j] = *(const float4*)&Pl[rr*S + c0 + 4*j];
    float e0  = (c0==0)  ? -INFINITY : row[0];
    float e17 = (c0==48) ? -INFINITY : row[17];
    #pragma unroll
    for(int i=0;i<16;i++){
      float lf = (i==0)  ? e0  : row[i];
      float rg = (i==15) ? e17 : row[i+2];
      s[i] += row[i]+row[i+1]+row[i+2];
      m[i] = fmaxf(m[i], fmaxf(lf, fmaxf(row[i+1], rg)));
    }
  }
  float sm=0,qm=0,sv=0,qv=0;
  #pragma unroll
  for(int i=0;i<16;i++){
    int c=c0+i;
    float cnt=(float)(rin*(3-(c==0)-(c==63)));
    float ap=s[i]/cnt, mp=m[i];
    sm+=mp; qm+=mp*mp; sv+=ap; qv+=ap*ap;
  }
  for(int o=32;o>0;o>>=1){
    sm+=__shfl_down(sm,o,64); qm+=__shfl_down(qm,o,64);
    sv+=__shfl_down(sv,o,64); qv+=__shfl_down(qv,o,64);
  }
  __shared__ float l[4][4];
  int lane=t&63, wv=t>>6;
  if(lane==0){ l[wv][0]=sm; l[wv][1]=qm; l[wv][2]=sv; l[wv][3]=qv; }
  __syncthreads();
  if(t==0){
    atomicAdd(&stats[p],     l[0][0]+l[1][0]+l[2][0]+l[3][0]);
    atomicAdd(&stats[128+p], l[0][1]+l[1][1]+l[2][1]+l[3][1]);
    atomicAdd(&stats[256+p], l[0][2]+l[1][2]+l[2][2]+l[3][2]);
    atomicAdd(&stats[384+p], l[0][3]+l[1][3]+l[2][3]+l[3][3]);
  }
}

// ---------------- dw core: depthwise conv on one bf16 (n,p) plane ----------
// Register-tiled; input bf16 plane; BN=1 applies (v-mean)*rstd before relu.
// IN-PLACE SAFE (src==outb): plane fully staged to LDS before any write.
template<int KS,int DIL,int BN>
DI void dw_core(float* Pl, const ush* src, const float* __restrict__ dww,
                const float* __restrict__ fin, int p,int n,int t, ush* outb){
  constexpr int R=(KS/2)*DIL;          // halo reach: 1,2,2,4
  constexpr int S=(R==4)?76:68;        // stride = 4 mod 32, 16B-aligned
  constexpr int NL=(16+2*R+3)/4;       // float4 loads per row (5 or 6)
  float mean=0.f, rstd=0.f;
  if constexpr(BN){ mean=fin[p]; rstd=fin[128+p]; }
  const ush* bp = src + ((size_t)n*128+p)*HWc;
  int px0=t*16;
  uint4 va=*(const uint4*)(bp+px0);
  uint4 vb=*(const uint4*)(bp+px0+8);
  float* dst=&Pl[(px0>>6)*S + R + (px0&63)];
  unsigned int wv8[8]={va.x,va.y,va.z,va.w,vb.x,vb.y,vb.z,vb.w};
  #pragma unroll
  for(int j=0;j<8;j++){
    float v0=u2f((ush)(wv8[j]&0xffff)), v1=u2f((ush)(wv8[j]>>16));
    if constexpr(BN){ v0=(v0-mean)*rstd; v1=(v1-mean)*rstd; }
    dst[2*j]  =fmaxf(v0,0.f);
    dst[2*j+1]=fmaxf(v1,0.f);
  }
  stage_pads<R,S>(Pl,t);
  __syncthreads();
  float wk[KS*KS];
  #pragma unroll
  for(int i=0;i<KS*KS;i++) wk[i]=dww[p*KS*KS+i];
  int r=t>>2, c0=(t&3)*16;
  float acc[16];
  #pragma unroll
  for(int i=0;i<16;i++) acc[i]=0.f;
  #pragma unroll
  for(int ky=0;ky<KS;ky++){
    int rr=r+(ky-KS/2)*DIL;
    if(rr<0||rr>=64) continue;
    float row[NL*4];
    #pragma unroll
    for(int j=0;j<NL;j++) *(float4*)&row[4*j] = *(const float4*)&Pl[rr*S + c0 + 4*j];
    #pragma unroll
    for(int kx=0;kx<KS;kx++){
      float wv=wk[ky*KS+kx];
      #pragma unroll
      for(int i=0;i<16;i++) acc[i]+=wv*row[R + i + (kx-KS/2)*DIL];
    }
  }
  ush* op = outb + ((size_t)n*128+p)*HWc + r*64 + c0;
  #pragma unroll
  for(int q=0;q<4;q++){
    ushort4 vv;
    vv.x=f2u(acc[4*q+0]); vv.y=f2u(acc[4*q+1]);
    vv.z=f2u(acc[4*q+2]); vv.w=f2u(acc[4*q+3]);
    *(ushort4*)(op+4*q)=vv;
  }
}

// ---------------- K_dw4: all four first-stage depthwise convs, z-batched ---
__global__ __launch_bounds__(256) void k_dw4(const ush* __restrict__ bufX,
    const float* __restrict__ s3d1,const float* __restrict__ s5d1,
    const float* __restrict__ d3dw,const float* __restrict__ d5dw,
    ush* __restrict__ bufA, ush* __restrict__ bufB,
    ush* __restrict__ bufC, ush* __restrict__ bufD){
  __shared__ float Pl[64*76];
  int p=blockIdx.x,n=blockIdx.y,t=threadIdx.x,z=blockIdx.z;
  if(z==0)      dw_core<3,1,0>(Pl,bufX,s3d1,nullptr,p,n,t,bufA);
  else if(z==1) dw_core<5,1,0>(Pl,bufX,s5d1,nullptr,p,n,t,bufB);
  else if(z==2) dw_core<3,2,0>(Pl,bufX,d3dw,nullptr,p,n,t,bufC);
  else          dw_core<5,2,0>(Pl,bufX,d5dw,nullptr,p,n,t,bufD);
}

// ---------------- K_dw2: second-stage depthwise (bn+relu), z-batched, in-place
__global__ __launch_bounds__(256) void k_dw2(ush* bufA, ush* bufB,
    const float* __restrict__ s3d2,const float* __restrict__ s5d2,
    const float* __restrict__ fin0,const float* __restrict__ fin2){
  __shared__ float Pl[64*68];
  int p=blockIdx.x,n=blockIdx.y,t=threadIdx.x,z=blockIdx.z;
  if(z==0) dw_core<3,1,1>(Pl,bufA,s3d2,fin0,p,n,t,bufA);
  else     dw_core<5,1,1>(Pl,bufB,s5d2,fin2,p,n,t,bufB);
}

// ---------------- pw core: pointwise 128->128 MFMA GEMM + bn stats ---------
// D[co][px] = sum_ci W[co][ci]*in[ci][px]. m92/m97-verified fragment layouts.
// bn-stats to 32-way sharded accumulators (Guideline 12). IN-PLACE SAFE.
DI void pw_core(ush (*Bt)[132], const ush* dwin, const ush* __restrict__ wt,
                ush* outb, float* __restrict__ shad, int bx,int by,int t){
  int n=by;
  int px0b = bx*64;
  const ush* dp = dwin + ((size_t)n*128)*HWc + px0b;
  #pragma unroll
  for(int k=0;k<4;k++){
    int e = t + k*256;                 // [0,1024)
    int c2 = e>>4;                     // ci pair 0..63
    int p4 = (e&15)*4;                 // px 0..60 step 4
    const ush* g0 = dp + (size_t)(2*c2)*HWc + p4;
    ushort4 va = *(const ushort4*)g0;
    ushort4 vb = *(const ushort4*)(g0 + HWc);
    *(unsigned int*)&Bt[p4+0][2*c2] = (unsigned int)va.x | ((unsigned int)vb.x<<16);
    *(unsigned int*)&Bt[p4+1][2*c2] = (unsigned int)va.y | ((unsigned int)vb.y<<16);
    *(unsigned int*)&Bt[p4+2][2*c2] = (unsigned int)va.z | ((unsigned int)vb.z<<16);
    *(unsigned int*)&Bt[p4+3][2*c2] = (unsigned int)va.w | ((unsigned int)vb.w<<16);
  }
  int lane=t&63, wv=t>>6;
  int co0=(wv>>1)*64, pxw=(wv&1)*32;   // wave tile: 64 co x 32 px
  int g=lane>>4, sl=lane&15;
  int arow = co0 + sl;
  int acg  = g*8;
  bf8 a[4][4];
  #pragma unroll
  for(int mt=0;mt<4;mt++)
    #pragma unroll
    for(int kt=0;kt<4;kt++)
      a[mt][kt] = *(const bf8*)(wt + (size_t)(arow+mt*16)*128 + kt*32 + acg);
  f4 acc[4][2] = {};
  __syncthreads();
  #pragma unroll
  for(int nt=0;nt<2;nt++){
    int pxl = pxw + nt*16 + sl;
    bf8 b[4];
    #pragma unroll
    for(int kt=0;kt<4;kt++){
      union { uint2 h[2]; bf8 v; } u;
      const ush* bp = &Bt[pxl][kt*32 + acg];
      u.h[0] = *(const uint2*)bp;
      u.h[1] = *(const uint2*)(bp+4);
      b[kt] = u.v;
    }
    #pragma unroll
    for(int kt=0;kt<4;kt++)
      #pragma unroll
      for(int mt=0;mt<4;mt++)
        acc[mt][nt] = __builtin_amdgcn_mfma_f32_16x16x32_bf16(a[mt][kt], b[kt], acc[mt][nt], 0,0,0);
  }
  float* sh = shad + (((bx + by)&31)*256);
  #pragma unroll
  for(int mt=0;mt<4;mt++){
    #pragma unroll
    for(int r=0;r<4;r++){
      int co = co0 + mt*16 + g*4 + r;
      float v0=acc[mt][0][r], v1=acc[mt][1][r];
      ush* ob = outb + ((size_t)n*128+co)*HWc + px0b + pxw;
      ob[sl]      = f2u(v0);
      ob[16+sl]   = f2u(v1);
      float s1 = v0+v1, s2 = v0*v0+v1*v1;
      #pragma unroll
      for(int o=1;o<16;o<<=1){ s1+=__shfl_xor(s1,o,64); s2+=__shfl_xor(s2,o,64); }
      if(sl==0){ atomicAdd(&sh[co],s1); atomicAdd(&sh[128+co],s2); }
    }
  }
}

// ---------------- K_pw4: z-batched pointwise MFMA (also used with z=2) -----
__global__ __launch_bounds__(256) void k_pw4(ush* bA, ush* bB, ush* bC, ush* bD,
    const ush* __restrict__ w0,const ush* __restrict__ w1,
    const ush* __restrict__ w2,const ush* __restrict__ w3,
    float* __restrict__ s0,float* __restrict__ s1,
    float* __restrict__ s2,float* __restrict__ s3){
  __shared__ ush Bt[64][132];
  int z=blockIdx.z;
  ush* b = z==0?bA:z==1?bB:z==2?bC:bD;
  const ush* wt = z==0?w0:z==1?w1:z==2?w2:w3;
  float* sh = z==0?s0:z==1?s1:z==2?s2:s3;
  pw_core(Bt,b,wt,b,sh,blockIdx.x,blockIdx.y,threadIdx.x);
}

// ---------------- K_statfin: fold 32 shards -> mean/rstd (z-batched) -------
__global__ void k_statfin4(const float* __restrict__ s0,const float* __restrict__ s1,
    const float* __restrict__ s2,const float* __restrict__ s3,
    float* __restrict__ f0,float* __restrict__ f1,
    float* __restrict__ f2,float* __restrict__ f3){
  int z=blockIdx.x, t=threadIdx.x;
  const float* shd = z==0?s0:z==1?s1:z==2?s2:s3;
  float* fin = z==0?f0:z==1?f1:z==2?f2:f3;
  if(t<128){
    float su=0.f, sq=0.f;
    #pragma unroll
    for(int j=0;j<32;j++){ su+=shd[j*256+t]; sq+=shd[j*256+128+t]; }
    float mean=su*RCNT, var=sq*RCNT-mean*mean;
    fin[t]=mean;
    fin[128+t]=rsqrtf(var+1e-5f);
  }
}

// ---------------- K_bacc: fused base + all four branch accumulates ---------
// out written exactly once: non-winning ch -> x*sa*att (f32 path);
// winning ch -> w3*xt + w1*bn(maxpool) + w2*bn(avgpool) + sum w[4..7]*bn(branch).
__global__ __launch_bounds__(256) void k_bacc(const float* __restrict__ x,
    const float* __restrict__ sa, const float* __restrict__ att,
    const int* __restrict__ nd, const int* __restrict__ dpos,
    const float* __restrict__ stats,
    const float* __restrict__ fin1,const float* __restrict__ fin3,
    const float* __restrict__ fin4,const float* __restrict__ fin5,
    const float* __restrict__ wts, const ush* __restrict__ bufX,
    const ush* __restrict__ brA,const ush* __restrict__ brB,
    const ush* __restrict__ brC,const ush* __restrict__ brD,
    float* __restrict__ out){
  constexpr int S=68;
  __shared__ float Pl[64*S];
  int ch=blockIdx.x, n=blockIdx.y, t=threadIdx.x;
  int p=dpos[ch];                      // block-uniform branch
  if(p<0){
    float a=att[n*128+ch];
    const float* xp=x+((size_t)n*128+ch)*HWc;
    const float* sp=sa+n*HWc;
    float* op=out+((size_t)n*128+ch)*HWc;
    int px0=t*16;
    #pragma unroll
    for(int j=0;j<4;j++){
      float4 xv=*(const float4*)(xp+px0+4*j);
      float4 sv=*(const float4*)(sp+px0+4*j);
      float4 ov;
      ov.x=xv.x*sv.x*a; ov.y=xv.y*sv.y*a; ov.z=xv.z*sv.z*a; ov.w=xv.w*sv.w*a;
      *(float4*)(op+px0+4*j)=ov;
    }
    return;
  }
  // stage xt plane (bf16) from bufX
  const ush* bxp=bufX+((size_t)n*128+p)*HWc;
  int px0=t*16;
  uint4 qa=*(const uint4*)(bxp+px0), qb=*(const uint4*)(bxp+px0+8);
  {
    float tv[16];
    unp8(qa,tv); unp8(qb,tv+8);
    float* dst=&Pl[(px0>>6)*S + 1 + (px0&63)];
    #pragma unroll
    for(int i=0;i<16;i++) dst[i]=tv[i];
  }
  stage_pads<1,S>(Pl,t);
  __syncthreads();
  float w1=wts[1],w2=wts[2],w3=wts[3],w4=wts[4],w5=wts[5],w6=wts[6],w7=wts[7];
  float m0,r0v,m1,r1v;
  { float su=stats[p],     sq=stats[128+p]; float mean=su*RCNT,var=sq*RCNT-mean*mean; m0=mean; r0v=rsqrtf(var+1e-5f); }
  { float su=stats[256+p], sq=stats[384+p]; float mean=su*RCNT,var=sq*RCNT-mean*mean; m1=mean; r1v=rsqrtf(var+1e-5f); }
  float mA=fin1[p],rA=fin1[128+p], mB=fin3[p],rB=fin3[128+p];
  float mC=fin4[p],rC=fin4[128+p], mD=fin5[p],rD=fin5[128+p];
  int r=t>>2, c0=(t&3)*16;
  float s[16], m[16], crow[16];
  #pragma unroll
  for(int i=0;i<16;i++){ s[i]=0.f; m[i]=-INFINITY; }
  int rin=0;
  #pragma unroll
  for(int ky=-1;ky<=1;ky++){
    int rr=r+ky;
    if(rr<0||rr>=64) continue;
    rin++;
    float row[20];
    #pragma unroll
    for(int j=0;j<5;j++) *(float4*)&row[4*j] = *(const float4*)&Pl[rr*S + c0 + 4*j];
    if(ky==0){
      #pragma unroll
      for(int i=0;i<16;i++) crow[i]=row[i+1];
    }
    float e0  = (c0==0)  ? -INFINITY : row[0];
    float e17 = (c0==48) ? -INFINITY : row[17];
    #pragma unroll
    for(int i=0;i<16;i++){
      float lf = (i==0)  ? e0  : row[i];
      float rg = (i==15) ? e17 : row[i+2];
      s[i] += row[i]+row[i+1]+row[i+2];
      m[i] = fmaxf(m[i], fmaxf(lf, fmaxf(row[i+1], rg)));
    }
  }
  float vout[16];
  #pragma unroll
  for(int i=0;i<16;i++){
    int c=c0+i;
    float cnt=(float)(rin*(3-(c==0)-(c==63)));
    float ap=s[i]/cnt;
    vout[i] = w3*crow[i] + w1*(m[i]-m0)*r0v + w2*(ap-m1)*r1v;
  }
  size_t boff=((size_t)n*128+p)*HWc + r*64 + c0;
  {
    float tv[16];
    unp8(*(const uint4*)(brA+boff),tv); unp8(*(const uint4*)(brA+boff+8),tv+8);
    #pragma unroll
    for(int i=0;i<16;i++) vout[i]+=w4*(tv[i]-mA)*rA;
    unp8(*(const uint4*)(brB+boff),tv); unp8(*(const uint4*)(brB+boff+8),tv+8);
    #pragma unroll
    for(int i=0;i<16;i++) vout[i]+=w5*(tv[i]-mB)*rB;
    unp8(*(const uint4*)(brC+boff),tv); unp8(*(const uint4*)(brC+boff+8),tv+8);
    #pragma unroll
    for(int i=0;i<16;i++) vout[i]+=w6*(tv[i]-mC)*rC;
    unp8(*(const uint4*)(brD+boff),tv); unp8(*(const uint4*)(brD+boff+8),tv+8);
    #pragma unroll
    for(int i=0;i<16;i++) vout[i]+=w7*(tv[i]-mD)*rD;
  }
  float* op=out+((size_t)n*128+ch)*HWc + r*64 + c0;
  #pragma unroll
  for(int q=0;q<4;q++) *(float4*)(op+4*q)=*(float4*)&vout[4*q];
}

extern "C" void kernel_launch(void* const* d_in, const int* in_sizes, int n_in,
                              void* d_out, int out_size, void* d_ws, size_t ws_size,
                              hipStream_t stream){
  (void)in_sizes; (void)n_in; (void)out_size;
  const float* x   =(const float*)d_in[0];
  const float* wts =(const float*)d_in[1];
  const float* fc1 =(const float*)d_in[2];
  const float* fc2 =(const float*)d_in[3];
  const float* saw =(const float*)d_in[4];
  const float* s3d1=(const float*)d_in[5];
  const float* s3p1=(const float*)d_in[6];
  const float* s3d2=(const float*)d_in[7];
  const float* s3p2=(const float*)d_in[8];
  const float* s5d1=(const float*)d_in[9];
  const float* s5p1=(const float*)d_in[10];
  const float* s5d2=(const float*)d_in[11];
  const float* s5p2=(const float*)d_in[12];
  const float* d3dw=(const float*)d_in[13];
  const float* d3pw=(const float*)d_in[14];
  const float* d5dw=(const float*)d_in[15];
  const float* d5pw=(const float*)d_in[16];
  const int* perm=(const int*)d_in[17];
  float* out=(float*)d_out;

  char* w=(char*)d_ws;
  float* stats=(float*)w;  w+=8192;
  float* smean=(float*)w;  w+=524288;
  float* smax =(float*)w;  w+=524288;
  float* sa   =(float*)w;  w+=524288;
  float* rsum =(float*)w;  w+=16384;
  float* rmax =(float*)w;  w+=16384;
  float* att  =(float*)w;  w+=16384;
  int*   nd   =(int*)w;    w+=512;
  int*   dpos =(int*)w;    w+=512;
  size_t small_bytes=(size_t)(w-(char*)d_ws);    // 1631232
  ush* bufA=(ush*)w;
  ush* bufB=(ush*)(w+BIG);
  ush* bufC=(ush*)(w+2*BIG);
  ush* bufD=(ush*)(w+3*BIG);
  ush* bufX=(ush*)(w+4*BIG);

  if(ws_size < small_bytes + 5*BIG){
    k_trivial<<<dim3(65536),dim3(256),0,stream>>>(out);
    return;
  }

  // bf16 pw weights in smean region (dead after k_sa). 6 x 32KB.
  ush* wb=(ush*)smean;
  ush* wb_s3p1=wb;
  ush* wb_s3p2=wb+16384;
  ush* wb_s5p1=wb+32768;
  ush* wb_s5p2=wb+49152;
  ush* wb_d3pw=wb+65536;
  ush* wb_d5pw=wb+81920;

  // 32-way sharded bn-stat accumulators in smax (dead after k_sa).
  float* shd0=smax;            // s3p1 (sep3 mid)
  float* shd1=smax+ 8192;      // s3p2 (sep3 final)
  float* shd2=smax+16384;      // s5p1 (sep5 mid)
  float* shd3=smax+24576;      // s5p2 (sep5 final)
  float* shd4=smax+32768;      // d3pw (dil3)
  float* shd5=smax+40960;      // d5pw (dil5)

  // finalized mean/rstd tables in the stats block
  float* fin0=stats+ 512;
  float* fin1=stats+ 768;
  float* fin2=stats+1024;
  float* fin3=stats+1280;
  float* fin4=stats+1536;
  float* fin5=stats+1792;

  dim3 B(256);
  dim3 Gpn(128,32);
  k_chan_reduce<<<dim3(16,32),B,0,stream>>>(x,smean,smax);
  k_sa<<<dim3(16,32),B,0,stream>>>(smean,smax,saw,sa);
  // smean/smax dead -> zero stats+shards, convert weights
  k_zero2<<<dim3(200),B,0,stream>>>(stats,smax);
  k_cvt6<<<dim3(64,6),B,0,stream>>>(s3p1,s3p2,s5p1,s5p2,d3pw,d5pw,wb);
  k_rowred<<<dim3(128,32),B,0,stream>>>(x,sa,rsum,rmax);
  k_mlp<<<dim3(32),B,0,stream>>>(rsum,rmax,fc1,fc2,att);
  k_topk<<<dim3(1),dim3(128),0,stream>>>(att,perm,nd,dpos);
  // xt materialize + fused poolstats
  k_xtps<<<Gpn,B,0,stream>>>(x,sa,att,nd,bufX,stats);
  // all four branch dw1 -> pw1 -> statfin
  k_dw4<<<dim3(128,32,4),B,0,stream>>>(bufX,s3d1,s5d1,d3dw,d5dw,bufA,bufB,bufC,bufD);
  k_pw4<<<dim3(64,32,4),B,0,stream>>>(bufA,bufB,bufC,bufD,
      wb_s3p1,wb_s5p1,wb_d3pw,wb_d5pw, shd0,shd2,shd4,shd5);
  k_statfin4<<<dim3(4),dim3(128),0,stream>>>(shd0,shd2,shd4,shd5,fin0,fin2,fin4,fin5);
  // sep second stage (in-place in bufA/bufB)
  k_dw2<<<dim3(128,32,2),B,0,stream>>>(bufA,bufB,s3d2,s5d2,fin0,fin2);
  k_pw4<<<dim3(64,32,2),B,0,stream>>>(bufA,bufB,bufA,bufA,
      wb_s3p2,wb_s5p2,wb_s3p2,wb_s3p2, shd1,shd3,shd1,shd1);
  k_statfin4<<<dim3(2),dim3(128),0,stream>>>(shd1,shd3,shd1,shd1,fin1,fin3,fin1,fin1);
  // fused base + 4-branch accumulate: single write of out
  k_bacc<<<Gpn,B,0,stream>>>(x,sa,att,nd,dpos,stats,fin1,fin3,fin4,fin5,
      wts,bufX,bufA,bufB,bufC,bufD,out);
}

// Round 8
// 470.541 us; speedup vs baseline: 1.9360x; 1.0191x over previous
//
#include <hip/hip_runtime.h>
#include <math.h>

#define DI __device__ __forceinline__
typedef unsigned short ush;

DI float u2f(ush u){ return __uint_as_float(((unsigned int)u)<<16); }
DI ush f2u(float f){ unsigned int u=__float_as_uint(f); u += 0x7fffu + ((u>>16)&1u); return (ush)(u>>16); }

constexpr int HWc = 4096;
constexpr float RCNT = 1.f/131072.f;      // 1 / (N*H*W)
constexpr size_t BIG = 33554432ull;       // [32][128][4096] bf16 bytes

typedef __attribute__((ext_vector_type(8))) __bf16 bf8;
typedef __attribute__((ext_vector_type(4))) float  f4;

DI void unp8(uint4 q, float* o){
  o[0]=u2f((ush)(q.x&0xffff)); o[1]=u2f((ush)(q.x>>16));
  o[2]=u2f((ush)(q.y&0xffff)); o[3]=u2f((ush)(q.y>>16));
  o[4]=u2f((ush)(q.z&0xffff)); o[5]=u2f((ush)(q.z>>16));
  o[6]=u2f((ush)(q.w&0xffff)); o[7]=u2f((ush)(q.w>>16));
}
DI uint4 pk8(const ush* u){
  uint4 q;
  q.x=(unsigned)u[0]|((unsigned)u[1]<<16); q.y=(unsigned)u[2]|((unsigned)u[3]<<16);
  q.z=(unsigned)u[4]|((unsigned)u[5]<<16); q.w=(unsigned)u[6]|((unsigned)u[7]<<16);
  return q;
}

// ---------------- K0: zero stats + stat shards in one pass -----------------
__global__ void k_zero2(float* __restrict__ a, float* __restrict__ b){
  int i=blockIdx.x*256+threadIdx.x;
  if(i<2048) a[i]=0.f;
  else if(i<2048+49152) b[i-2048]=0.f;
}

// ---------------- fallback: zero-fill output (clean diagnostic failure) ----
__global__ void k_trivial(float* __restrict__ out){
  size_t i=(size_t)blockIdx.x*256+threadIdx.x;
  if(i<16777216ull) out[i]=0.f;
}

// ---------------- K1: per-pixel channel mean/max ---------------------------
__global__ void k_chan_reduce(const float* __restrict__ x, float* __restrict__ smean, float* __restrict__ smax){
  int n = blockIdx.y;
  int px = blockIdx.x*256 + threadIdx.x;
  const float* xp = x + ((size_t)n*128)*HWc + px;
  float s=0.f, m=-INFINITY;
  #pragma unroll 8
  for(int c=0;c<128;c++){ float v=xp[(size_t)c*HWc]; s+=v; m=fmaxf(m,v); }
  smean[n*HWc+px]=s*(1.f/128.f);
  smax[n*HWc+px]=m;
}

// ---------------- K2: 7x7 conv (2->1 ch) + sigmoid -> sa -------------------
__global__ void k_sa(const float* __restrict__ smean, const float* __restrict__ smax,
                     const float* __restrict__ w, float* __restrict__ sa){
  __shared__ float wm[49], wx[49];
  int t=threadIdx.x;
  if(t<49) wm[t]=w[t];
  else if(t<98) wx[t-49]=w[t];
  __syncthreads();
  int n=blockIdx.y;
  int px=blockIdx.x*256+t;
  int r=px>>6, c=px&63;
  const float* pm  = smean + n*HWc;
  const float* pxm = smax  + n*HWc;
  float acc=0.f;
  for(int ky=0;ky<7;ky++){
    int rr=r+ky-3; if(rr<0||rr>=64) continue;
    for(int kx=0;kx<7;kx++){
      int cc=c+kx-3; if(cc<0||cc>=64) continue;
      int q=(rr<<6)+cc;
      acc += wm[ky*7+kx]*pm[q] + wx[ky*7+kx]*pxm[q];
    }
  }
  sa[n*HWc+px] = 1.f/(1.f+expf(-acc));
}

// ---------------- K3: per-(n,c) sum/max over HW of x*sa --------------------
__global__ void k_rowred(const float* __restrict__ x, const float* __restrict__ sa,
                         float* __restrict__ rsum, float* __restrict__ rmax){
  int c=blockIdx.x, n=blockIdx.y;
  const float* xp = x + ((size_t)n*128 + c)*HWc;
  const float* sp = sa + n*HWc;
  float s=0.f, m=-INFINITY;
  for(int i=threadIdx.x;i<HWc;i+=256){
    float v=xp[i]*sp[i]; s+=v; m=fmaxf(m,v);
  }
  __shared__ float ls[4], lm[4];
  for(int o=32;o>0;o>>=1){ s+=__shfl_down(s,o,64); m=fmaxf(m,__shfl_down(m,o,64)); }
  int lane=threadIdx.x&63, wv=threadIdx.x>>6;
  if(lane==0){ ls[wv]=s; lm[wv]=m; }
  __syncthreads();
  if(threadIdx.x==0){
    rsum[n*128+c]=ls[0]+ls[1]+ls[2]+ls[3];
    rmax[n*128+c]=fmaxf(fmaxf(lm[0],lm[1]),fmaxf(lm[2],lm[3]));
  }
}

// ---------------- K4a: channel-attention MLP per n -------------------------
__global__ void k_mlp(const float* __restrict__ rsum, const float* __restrict__ rmax,
                      const float* __restrict__ fc1, const float* __restrict__ fc2,
                      float* __restrict__ att){
  int n=blockIdx.x, t=threadIdx.x;
  __shared__ float zm[128], zx[128], hm[64], hx[64];
  if(t<128){ zm[t]=rsum[n*128+t]*(1.f/4096.f); zx[t]=rmax[n*128+t]; }
  __syncthreads();
  if(t<64){
    float a=0.f;
    for(int c=0;c<128;c++) a+=fc1[t*128+c]*zm[c];
    hm[t]=fmaxf(a,0.f);
  } else if(t<128){
    int j=t-64; float a=0.f;
    for(int c=0;c<128;c++) a+=fc1[j*128+c]*zx[c];
    hx[j]=fmaxf(a,0.f);
  }
  __syncthreads();
  if(t<128){
    float a=0.f,b=0.f;
    for(int j=0;j<64;j++){ float wv=fc2[t*64+j]; a+=wv*hm[j]; b+=wv*hx[j]; }
    att[n*128+t]=1.f/(1.f+expf(-(a+b)));
  }
}

// ---------------- K4b: slist, top-96, num_dict, last-occurrence map --------
__global__ void k_topk(const float* __restrict__ att, const int* __restrict__ perm,
                       int* __restrict__ nd_out, int* __restrict__ dst_pos){
  __shared__ float sl[128];
  __shared__ int nd[128];
  int t=threadIdx.x;          // 128 threads
  float s=0.f;
  for(int n=0;n<32;n++) s+=att[n*128+t];
  sl[t]=s;
  nd[t]=t;
  __syncthreads();
  float v=sl[t]; int r=0;
  for(int c=0;c<128;c++){ float u=sl[c]; r += ((u>v) || (u==v && c<t)) ? 1 : 0; }
  if(r<96) nd[r]=t;
  __syncthreads();
  if(t<32) nd[96+t]=perm[t]&127;
  __syncthreads();
  nd_out[t]=nd[t]&127;
  int pos=-1;
  for(int p=0;p<128;p++) if((nd[p]&127)==t) pos=p;
  dst_pos[t]=pos;
}

// ---------------- zero the halo pad columns of a padded LDS plane ----------
template<int R,int S>
DI void stage_pads(float* __restrict__ Pl, int t){
  if(t<64){
    #pragma unroll
    for(int j=0;j<R;j++) Pl[t*S+j]=0.f;
    #pragma unroll
    for(int j=64+R;j<S;j++) Pl[t*S+j]=0.f;
  }
}

// ---------------- K_cvt6: 6x f32->bf16 weight convert in one launch --------
__global__ void k_cvt6(const float* __restrict__ a,const float* __restrict__ b,
    const float* __restrict__ c,const float* __restrict__ d,
    const float* __restrict__ e,const float* __restrict__ f,
    ush* __restrict__ wb){
  int z=blockIdx.y;
  const float* src = z==0?a:z==1?b:z==2?c:z==3?d:z==4?e:f;
  int i=blockIdx.x*256+threadIdx.x;
  wb[z*16384+i]=f2u(src[i]);
}

// ---------------- K_xtps: xt = bf16(x[nd[p]]*sa*att) + fused poolstats -----
__global__ __launch_bounds__(256) void k_xtps(const float* __restrict__ x,
    const float* __restrict__ sa, const float* __restrict__ att,
    const int* __restrict__ nd, ush* __restrict__ bufX, float* __restrict__ stats){
  constexpr int S=68;
  __shared__ float Pl[64*S];
  int p=blockIdx.x, n=blockIdx.y, t=threadIdx.x;
  int ch=nd[p]&127;
  float a=att[n*128+ch];
  const float* xp=x+((size_t)n*128+ch)*HWc;
  const float* sp=sa+n*HWc;
  int px0=t*16;
  ush u[16];
  #pragma unroll
  for(int j=0;j<4;j++){
    float4 xv=*(const float4*)(xp+px0+4*j);
    float4 sv=*(const float4*)(sp+px0+4*j);
    u[4*j+0]=f2u(xv.x*sv.x*a); u[4*j+1]=f2u(xv.y*sv.y*a);
    u[4*j+2]=f2u(xv.z*sv.z*a); u[4*j+3]=f2u(xv.w*sv.w*a);
  }
  ush* bo=bufX+((size_t)n*128+p)*HWc+px0;
  *(uint4*)bo   = pk8(u);
  *(uint4*)(bo+8)= pk8(u+8);
  float* dst=&Pl[(px0>>6)*S + 1 + (px0&63)];
  #pragma unroll
  for(int i=0;i<16;i++) dst[i]=u2f(u[i]);
  stage_pads<1,S>(Pl,t);
  __syncthreads();
  int r=t>>2, c0=(t&3)*16;
  float s[16], m[16];
  #pragma unroll
  for(int i=0;i<16;i++){ s[i]=0.f; m[i]=-INFINITY; }
  int rin=0;
  #pragma unroll
  for(int ky=-1;ky<=1;ky++){
    int rr=r+ky;
    if(rr<0||rr>=64) continue;
    rin++;
    float row[20];
    #pragma unroll
    for(int j=0;j<5;j++) *(float4*)&row[4*j] = *(const float4*)&Pl[rr*S + c0 + 4*j];
    float e0  = (c0==0)  ? -INFINITY : row[0];
    float e17 = (c0==48) ? -INFINITY : row[17];
    #pragma unroll
    for(int i=0;i<16;i++){
      float lf = (i==0)  ? e0  : row[i];
      float rg = (i==15) ? e17 : row[i+2];
      s[i] += row[i]+row[i+1]+row[i+2];
      m[i] = fmaxf(m[i], fmaxf(lf, fmaxf(row[i+1], rg)));
    }
  }
  float sm=0,qm=0,sv=0,qv=0;
  #pragma unroll
  for(int i=0;i<16;i++){
    int c=c0+i;
    float cnt=(float)(rin*(3-(c==0)-(c==63)));
    float ap=s[i]/cnt, mp=m[i];
    sm+=mp; qm+=mp*mp; sv+=ap; qv+=ap*ap;
  }
  for(int o=32;o>0;o>>=1){
    sm+=__shfl_down(sm,o,64); qm+=__shfl_down(qm,o,64);
    sv+=__shfl_down(sv,o,64); qv+=__shfl_down(qv,o,64);
  }
  __shared__ float l[4][4];
  int lane=t&63, wv=t>>6;
  if(lane==0){ l[wv][0]=sm; l[wv][1]=qm; l[wv][2]=sv; l[wv][3]=qv; }
  __syncthreads();
  if(t==0){
    atomicAdd(&stats[p],     l[0][0]+l[1][0]+l[2][0]+l[3][0]);
    atomicAdd(&stats[128+p], l[0][1]+l[1][1]+l[2][1]+l[3][1]);
    atomicAdd(&stats[256+p], l[0][2]+l[1][2]+l[2][2]+l[3][2]);
    atomicAdd(&stats[384+p], l[0][3]+l[1][3]+l[2][3]+l[3][3]);
  }
}

// ---------------- dw core: depthwise conv on one bf16 (n,p) plane ----------
template<int KS,int DIL,int BN>
DI void dw_core(float* Pl, const ush* src, const float* __restrict__ dww,
                const float* __restrict__ fin, int p,int n,int t, ush* outb){
  constexpr int R=(KS/2)*DIL;          // halo reach: 1,2,2,4
  constexpr int S=(R==4)?76:68;        // stride = 4 mod 32, 16B-aligned
  constexpr int NL=(16+2*R+3)/4;       // float4 loads per row (5 or 6)
  float mean=0.f, rstd=0.f;
  if constexpr(BN){ mean=fin[p]; rstd=fin[128+p]; }
  const ush* bp = src + ((size_t)n*128+p)*HWc;
  int px0=t*16;
  uint4 va=*(const uint4*)(bp+px0);
  uint4 vb=*(const uint4*)(bp+px0+8);
  float* dst=&Pl[(px0>>6)*S + R + (px0&63)];
  unsigned int wv8[8]={va.x,va.y,va.z,va.w,vb.x,vb.y,vb.z,vb.w};
  #pragma unroll
  for(int j=0;j<8;j++){
    float v0=u2f((ush)(wv8[j]&0xffff)), v1=u2f((ush)(wv8[j]>>16));
    if constexpr(BN){ v0=(v0-mean)*rstd; v1=(v1-mean)*rstd; }
    dst[2*j]  =fmaxf(v0,0.f);
    dst[2*j+1]=fmaxf(v1,0.f);
  }
  stage_pads<R,S>(Pl,t);
  __syncthreads();
  float wk[KS*KS];
  #pragma unroll
  for(int i=0;i<KS*KS;i++) wk[i]=dww[p*KS*KS+i];
  int r=t>>2, c0=(t&3)*16;
  float acc[16];
  #pragma unroll
  for(int i=0;i<16;i++) acc[i]=0.f;
  #pragma unroll
  for(int ky=0;ky<KS;ky++){
    int rr=r+(ky-KS/2)*DIL;
    if(rr<0||rr>=64) continue;
    float row[NL*4];
    #pragma unroll
    for(int j=0;j<NL;j++) *(float4*)&row[4*j] = *(const float4*)&Pl[rr*S + c0 + 4*j];
    #pragma unroll
    for(int kx=0;kx<KS;kx++){
      float wv=wk[ky*KS+kx];
      #pragma unroll
      for(int i=0;i<16;i++) acc[i]+=wv*row[R + i + (kx-KS/2)*DIL];
    }
  }
  ush* op = outb + ((size_t)n*128+p)*HWc + r*64 + c0;
  #pragma unroll
  for(int q=0;q<4;q++){
    ushort4 vv;
    vv.x=f2u(acc[4*q+0]); vv.y=f2u(acc[4*q+1]);
    vv.z=f2u(acc[4*q+2]); vv.w=f2u(acc[4*q+3]);
    *(ushort4*)(op+4*q)=vv;
  }
}

// ---------------- K_dw4: all four first-stage depthwise convs, z-batched ---
__global__ __launch_bounds__(256) void k_dw4(const ush* __restrict__ bufX,
    const float* __restrict__ s3d1,const float* __restrict__ s5d1,
    const float* __restrict__ d3dw,const float* __restrict__ d5dw,
    ush* __restrict__ bufA, ush* __restrict__ bufB,
    ush* __restrict__ bufC, ush* __restrict__ bufD){
  __shared__ float Pl[64*76];
  int p=blockIdx.x,n=blockIdx.y,t=threadIdx.x,z=blockIdx.z;
  if(z==0)      dw_core<3,1,0>(Pl,bufX,s3d1,nullptr,p,n,t,bufA);
  else if(z==1) dw_core<5,1,0>(Pl,bufX,s5d1,nullptr,p,n,t,bufB);
  else if(z==2) dw_core<3,2,0>(Pl,bufX,d3dw,nullptr,p,n,t,bufC);
  else          dw_core<5,2,0>(Pl,bufX,d5dw,nullptr,p,n,t,bufD);
}

// ---------------- K_dw2: second-stage depthwise (bn+relu), z-batched, in-place
__global__ __launch_bounds__(256) void k_dw2(ush* bufA, ush* bufB,
    const float* __restrict__ s3d2,const float* __restrict__ s5d2,
    const float* __restrict__ fin0,const float* __restrict__ fin2){
  __shared__ float Pl[64*68];
  int p=blockIdx.x,n=blockIdx.y,t=threadIdx.x,z=blockIdx.z;
  if(z==0) dw_core<3,1,1>(Pl,bufA,s3d2,fin0,p,n,t,bufA);
  else     dw_core<5,1,1>(Pl,bufB,s5d2,fin2,p,n,t,bufB);
}

// ---------------- pw core: pointwise 128->128 MFMA GEMM + bn stats ---------
// D[co][px] = sum_ci W[co][ci]*in[ci][px]. m92/m97-verified fragment layouts.
// NEW epilogue: acc -> LDS f32 tile [co][66] (aliases Bt, dead after frag
// loads) -> per-co linear pass: local stats (1 shfl pair, replaces 128
// shuffles) + full-128B-line bf16 stores (kills the 1.5x write amplification
// seen in round 7: WRITE_SIZE 196MB vs 128MB logical). IN-PLACE SAFE.
DI void pw_core(char* pool, const ush* dwin, const ush* __restrict__ wt,
                ush* outb, float* __restrict__ shad, int bx,int by,int t){
  ush (*Bt)[132] = (ush(*)[132])pool;   // 64 x 132 ush = 16896 B
  float* Lf = (float*)pool;             // 128 x 66 f32 = 33792 B (after barrier)
  int n=by;
  int px0b = bx*64;
  const ush* dp = dwin + ((size_t)n*128)*HWc + px0b;
  #pragma unroll
  for(int k=0;k<4;k++){
    int e = t + k*256;                 // [0,1024)
    int c2 = e>>4;                     // ci pair 0..63
    int p4 = (e&15)*4;                 // px 0..60 step 4
    const ush* g0 = dp + (size_t)(2*c2)*HWc + p4;
    ushort4 va = *(const ushort4*)g0;
    ushort4 vb = *(const ushort4*)(g0 + HWc);
    *(unsigned int*)&Bt[p4+0][2*c2] = (unsigned int)va.x | ((unsigned int)vb.x<<16);
    *(unsigned int*)&Bt[p4+1][2*c2] = (unsigned int)va.y | ((unsigned int)vb.y<<16);
    *(unsigned int*)&Bt[p4+2][2*c2] = (unsigned int)va.z | ((unsigned int)vb.z<<16);
    *(unsigned int*)&Bt[p4+3][2*c2] = (unsigned int)va.w | ((unsigned int)vb.w<<16);
  }
  int lane=t&63, wv=t>>6;
  int co0=(wv>>1)*64, pxw=(wv&1)*32;   // wave tile: 64 co x 32 px
  int g=lane>>4, sl=lane&15;
  int arow = co0 + sl;
  int acg  = g*8;
  bf8 a[4][4];
  #pragma unroll
  for(int mt=0;mt<4;mt++)
    #pragma unroll
    for(int kt=0;kt<4;kt++)
      a[mt][kt] = *(const bf8*)(wt + (size_t)(arow+mt*16)*128 + kt*32 + acg);
  f4 acc[4][2] = {};
  __syncthreads();
  #pragma unroll
  for(int nt=0;nt<2;nt++){
    int pxl = pxw + nt*16 + sl;
    bf8 b[4];
    #pragma unroll
    for(int kt=0;kt<4;kt++){
      union { uint2 h[2]; bf8 v; } u;
      const ush* bp = &Bt[pxl][kt*32 + acg];
      u.h[0] = *(const uint2*)bp;
      u.h[1] = *(const uint2*)(bp+4);
      b[kt] = u.v;
    }
    #pragma unroll
    for(int kt=0;kt<4;kt++)
      #pragma unroll
      for(int mt=0;mt<4;mt++)
        acc[mt][nt] = __builtin_amdgcn_mfma_f32_16x16x32_bf16(a[mt][kt], b[kt], acc[mt][nt], 0,0,0);
  }
  // ---- epilogue: transpose through LDS ----
  __syncthreads();                     // all Bt reads complete before overwrite
  #pragma unroll
  for(int mt=0;mt<4;mt++)
    #pragma unroll
    for(int r=0;r<4;r++){
      int co = co0 + mt*16 + g*4 + r;
      Lf[co*66 + pxw + sl]      = acc[mt][0][r];
      Lf[co*66 + pxw + 16 + sl] = acc[mt][1][r];
    }
  __syncthreads();
  int co=t>>1, half=t&1;
  const float* Lr = &Lf[co*66 + half*32];
  float s1=0.f, s2=0.f;
  ush ob16[32];
  #pragma unroll
  for(int j=0;j<16;j++){
    float2 v=*(const float2*)(Lr+2*j);
    s1+=v.x+v.y; s2+=v.x*v.x+v.y*v.y;
    ob16[2*j]=f2u(v.x); ob16[2*j+1]=f2u(v.y);
  }
  s1+=__shfl_xor(s1,1,64); s2+=__shfl_xor(s2,1,64);
  ush* op = outb + ((size_t)n*128+co)*HWc + px0b + half*32;
  *(uint4*)op      = pk8(ob16);
  *(uint4*)(op+8)  = pk8(ob16+8);
  *(uint4*)(op+16) = pk8(ob16+16);
  *(uint4*)(op+24) = pk8(ob16+24);
  float* sh = shad + (((bx + by)&31)*256);
  if(half==0){ atomicAdd(&sh[co],s1); atomicAdd(&sh[128+co],s2); }
}

// ---------------- K_pw4: z-batched pointwise MFMA (also used with z=2) -----
__global__ __launch_bounds__(256) void k_pw4(ush* bA, ush* bB, ush* bC, ush* bD,
    const ush* __restrict__ w0,const ush* __restrict__ w1,
    const ush* __restrict__ w2,const ush* __restrict__ w3,
    float* __restrict__ s0,float* __restrict__ s1,
    float* __restrict__ s2,float* __restrict__ s3){
  __shared__ __align__(16) char pool[33792];
  int z=blockIdx.z;
  ush* b = z==0?bA:z==1?bB:z==2?bC:bD;
  const ush* wt = z==0?w0:z==1?w1:z==2?w2:w3;
  float* sh = z==0?s0:z==1?s1:z==2?s2:s3;
  pw_core(pool,b,wt,b,sh,blockIdx.x,blockIdx.y,threadIdx.x);
}

// ---------------- K_statfin: fold 32 shards -> mean/rstd (z-batched) -------
__global__ void k_statfin4(const float* __restrict__ s0,const float* __restrict__ s1,
    const float* __restrict__ s2,const float* __restrict__ s3,
    float* __restrict__ f0,float* __restrict__ f1,
    float* __restrict__ f2,float* __restrict__ f3){
  int z=blockIdx.x, t=threadIdx.x;
  const float* shd = z==0?s0:z==1?s1:z==2?s2:s3;
  float* fin = z==0?f0:z==1?f1:z==2?f2:f3;
  if(t<128){
    float su=0.f, sq=0.f;
    #pragma unroll
    for(int j=0;j<32;j++){ su+=shd[j*256+t]; sq+=shd[j*256+128+t]; }
    float mean=su*RCNT, var=sq*RCNT-mean*mean;
    fin[t]=mean;
    fin[128+t]=rsqrtf(var+1e-5f);
  }
}

// ---------------- K_bacc: fused base + all four branch accumulates ---------
__global__ __launch_bounds__(256) void k_bacc(const float* __restrict__ x,
    const float* __restrict__ sa, const float* __restrict__ att,
    const int* __restrict__ nd, const int* __restrict__ dpos,
    const float* __restrict__ stats,
    const float* __restrict__ fin1,const float* __restrict__ fin3,
    const float* __restrict__ fin4,const float* __restrict__ fin5,
    const float* __restrict__ wts, const ush* __restrict__ bufX,
    const ush* __restrict__ brA,const ush* __restrict__ brB,
    const ush* __restrict__ brC,const ush* __restrict__ brD,
    float* __restrict__ out){
  constexpr int S=68;
  __shared__ float Pl[64*S];
  int ch=blockIdx.x, n=blockIdx.y, t=threadIdx.x;
  int p=dpos[ch];                      // block-uniform branch
  if(p<0){
    float a=att[n*128+ch];
    const float* xp=x+((size_t)n*128+ch)*HWc;
    const float* sp=sa+n*HWc;
    float* op=out+((size_t)n*128+ch)*HWc;
    int px0=t*16;
    #pragma unroll
    for(int j=0;j<4;j++){
      float4 xv=*(const float4*)(xp+px0+4*j);
      float4 sv=*(const float4*)(sp+px0+4*j);
      float4 ov;
      ov.x=xv.x*sv.x*a; ov.y=xv.y*sv.y*a; ov.z=xv.z*sv.z*a; ov.w=xv.w*sv.w*a;
      *(float4*)(op+px0+4*j)=ov;
    }
    return;
  }
  // stage xt plane (bf16) from bufX
  const ush* bxp=bufX+((size_t)n*128+p)*HWc;
  int px0=t*16;
  uint4 qa=*(const uint4*)(bxp+px0), qb=*(const uint4*)(bxp+px0+8);
  {
    float tv[16];
    unp8(qa,tv); unp8(qb,tv+8);
    float* dst=&Pl[(px0>>6)*S + 1 + (px0&63)];
    #pragma unroll
    for(int i=0;i<16;i++) dst[i]=tv[i];
  }
  stage_pads<1,S>(Pl,t);
  __syncthreads();
  float w1=wts[1],w2=wts[2],w3=wts[3],w4=wts[4],w5=wts[5],w6=wts[6],w7=wts[7];
  float m0,r0v,m1,r1v;
  { float su=stats[p],     sq=stats[128+p]; float mean=su*RCNT,var=sq*RCNT-mean*mean; m0=mean; r0v=rsqrtf(var+1e-5f); }
  { float su=stats[256+p], sq=stats[384+p]; float mean=su*RCNT,var=sq*RCNT-mean*mean; m1=mean; r1v=rsqrtf(var+1e-5f); }
  float mA=fin1[p],rA=fin1[128+p], mB=fin3[p],rB=fin3[128+p];
  float mC=fin4[p],rC=fin4[128+p], mD=fin5[p],rD=fin5[128+p];
  int r=t>>2, c0=(t&3)*16;
  float s[16], m[16], crow[16];
  #pragma unroll
  for(int i=0;i<16;i++){ s[i]=0.f; m[i]=-INFINITY; }
  int rin=0;
  #pragma unroll
  for(int ky=-1;ky<=1;ky++){
    int rr=r+ky;
    if(rr<0||rr>=64) continue;
    rin++;
    float row[20];
    #pragma unroll
    for(int j=0;j<5;j++) *(float4*)&row[4*j] = *(const float4*)&Pl[rr*S + c0 + 4*j];
    if(ky==0){
      #pragma unroll
      for(int i=0;i<16;i++) crow[i]=row[i+1];
    }
    float e0  = (c0==0)  ? -INFINITY : row[0];
    float e17 = (c0==48) ? -INFINITY : row[17];
    #pragma unroll
    for(int i=0;i<16;i++){
      float lf = (i==0)  ? e0  : row[i];
      float rg = (i==15) ? e17 : row[i+2];
      s[i] += row[i]+row[i+1]+row[i+2];
      m[i] = fmaxf(m[i], fmaxf(lf, fmaxf(row[i+1], rg)));
    }
  }
  float vout[16];
  #pragma unroll
  for(int i=0;i<16;i++){
    int c=c0+i;
    float cnt=(float)(rin*(3-(c==0)-(c==63)));
    float ap=s[i]/cnt;
    vout[i] = w3*crow[i] + w1*(m[i]-m0)*r0v + w2*(ap-m1)*r1v;
  }
  size_t boff=((size_t)n*128+p)*HWc + r*64 + c0;
  {
    float tv[16];
    unp8(*(const uint4*)(brA+boff),tv); unp8(*(const uint4*)(brA+boff+8),tv+8);
    #pragma unroll
    for(int i=0;i<16;i++) vout[i]+=w4*(tv[i]-mA)*rA;
    unp8(*(const uint4*)(brB+boff),tv); unp8(*(const uint4*)(brB+boff+8),tv+8);
    #pragma unroll
    for(int i=0;i<16;i++) vout[i]+=w5*(tv[i]-mB)*rB;
    unp8(*(const uint4*)(brC+boff),tv); unp8(*(const uint4*)(brC+boff+8),tv+8);
    #pragma unroll
    for(int i=0;i<16;i++) vout[i]+=w6*(tv[i]-mC)*rC;
    unp8(*(const uint4*)(brD+boff),tv); unp8(*(const uint4*)(brD+boff+8),tv+8);
    #pragma unroll
    for(int i=0;i<16;i++) vout[i]+=w7*(tv[i]-mD)*rD;
  }
  float* op=out+((size_t)n*128+ch)*HWc + r*64 + c0;
  #pragma unroll
  for(int q=0;q<4;q++) *(float4*)(op+4*q)=*(float4*)&vout[4*q];
}

extern "C" void kernel_launch(void* const* d_in, const int* in_sizes, int n_in,
                              void* d_out, int out_size, void* d_ws, size_t ws_size,
                              hipStream_t stream){
  (void)in_sizes; (void)n_in; (void)out_size;
  const float* x   =(const float*)d_in[0];
  const float* wts =(const float*)d_in[1];
  const float* fc1 =(const float*)d_in[2];
  const float* fc2 =(const float*)d_in[3];
  const float* saw =(const float*)d_in[4];
  const float* s3d1=(const float*)d_in[5];
  const float* s3p1=(const float*)d_in[6];
  const float* s3d2=(const float*)d_in[7];
  const float* s3p2=(const float*)d_in[8];
  const float* s5d1=(const float*)d_in[9];
  const float* s5p1=(const float*)d_in[10];
  const float* s5d2=(const float*)d_in[11];
  const float* s5p2=(const float*)d_in[12];
  const float* d3dw=(const float*)d_in[13];
  const float* d3pw=(const float*)d_in[14];
  const float* d5dw=(const float*)d_in[15];
  const float* d5pw=(const float*)d_in[16];
  const int* perm=(const int*)d_in[17];
  float* out=(float*)d_out;

  char* w=(char*)d_ws;
  float* stats=(float*)w;  w+=8192;
  float* smean=(float*)w;  w+=524288;
  float* smax =(float*)w;  w+=524288;
  float* sa   =(float*)w;  w+=524288;
  float* rsum =(float*)w;  w+=16384;
  float* rmax =(float*)w;  w+=16384;
  float* att  =(float*)w;  w+=16384;
  int*   nd   =(int*)w;    w+=512;
  int*   dpos =(int*)w;    w+=512;
  size_t small_bytes=(size_t)(w-(char*)d_ws);    // 1631232
  ush* bufA=(ush*)w;
  ush* bufB=(ush*)(w+BIG);
  ush* bufC=(ush*)(w+2*BIG);
  ush* bufD=(ush*)(w+3*BIG);
  ush* bufX=(ush*)(w+4*BIG);

  if(ws_size < small_bytes + 5*BIG){
    k_trivial<<<dim3(65536),dim3(256),0,stream>>>(out);
    return;
  }

  // bf16 pw weights in smean region (dead after k_sa). 6 x 32KB.
  ush* wb=(ush*)smean;
  ush* wb_s3p1=wb;
  ush* wb_s3p2=wb+16384;
  ush* wb_s5p1=wb+32768;
  ush* wb_s5p2=wb+49152;
  ush* wb_d3pw=wb+65536;
  ush* wb_d5pw=wb+81920;

  // 32-way sharded bn-stat accumulators in smax (dead after k_sa).
  float* shd0=smax;            // s3p1 (sep3 mid)
  float* shd1=smax+ 8192;      // s3p2 (sep3 final)
  float* shd2=smax+16384;      // s5p1 (sep5 mid)
  float* shd3=smax+24576;      // s5p2 (sep5 final)
  float* shd4=smax+32768;      // d3pw (dil3)
  float* shd5=smax+40960;      // d5pw (dil5)

  // finalized mean/rstd tables in the stats block
  float* fin0=stats+ 512;
  float* fin1=stats+ 768;
  float* fin2=stats+1024;
  float* fin3=stats+1280;
  float* fin4=stats+1536;
  float* fin5=stats+1792;

  dim3 B(256);
  dim3 Gpn(128,32);
  k_chan_reduce<<<dim3(16,32),B,0,stream>>>(x,smean,smax);
  k_sa<<<dim3(16,32),B,0,stream>>>(smean,smax,saw,sa);
  // smean/smax dead -> zero stats+shards, convert weights
  k_zero2<<<dim3(200),B,0,stream>>>(stats,smax);
  k_cvt6<<<dim3(64,6),B,0,stream>>>(s3p1,s3p2,s5p1,s5p2,d3pw,d5pw,wb);
  k_rowred<<<dim3(128,32),B,0,stream>>>(x,sa,rsum,rmax);
  k_mlp<<<dim3(32),B,0,stream>>>(rsum,rmax,fc1,fc2,att);
  k_topk<<<dim3(1),dim3(128),0,stream>>>(att,perm,nd,dpos);
  // xt materialize + fused poolstats
  k_xtps<<<Gpn,B,0,stream>>>(x,sa,att,nd,bufX,stats);
  // all four branch dw1 -> pw1 -> statfin
  k_dw4<<<dim3(128,32,4),B,0,stream>>>(bufX,s3d1,s5d1,d3dw,d5dw,bufA,bufB,bufC,bufD);
  k_pw4<<<dim3(64,32,4),B,0,stream>>>(bufA,bufB,bufC,bufD,
      wb_s3p1,wb_s5p1,wb_d3pw,wb_d5pw, shd0,shd2,shd4,shd5);
  k_statfin4<<<dim3(4),dim3(128),0,stream>>>(shd0,shd2,shd4,shd5,fin0,fin2,fin4,fin5);
  // sep second stage (in-place in bufA/bufB)
  k_dw2<<<dim3(128,32,2),B,0,stream>>>(bufA,bufB,s3d2,s5d2,fin0,fin2);
  k_pw4<<<dim3(64,32,2),B,0,stream>>>(bufA,bufB,bufA,bufA,
      wb_s3p2,wb_s5p2,wb_s3p2,wb_s3p2, shd1,shd3,shd1,shd1);
  k_statfin4<<<dim3(2),dim3(128),0,stream>>>(shd1,shd3,shd1,shd1,fin1,fin3,fin1,fin1);
  // fused base + 4-branch accumulate: single write of out
  k_bacc<<<Gpn,B,0,stream>>>(x,sa,att,nd,dpos,stats,fin1,fin3,fin4,fin5,
      wts,bufX,bufA,bufB,bufC,bufD,out);
}

// Round 9
// 459.415 us; speedup vs baseline: 1.9829x; 1.0242x over previous
//
#include <hip/hip_runtime.h>
#include <math.h>

#define DI __device__ __forceinline__
typedef unsigned short ush;

DI float u2f(ush u){ return __uint_as_float(((unsigned int)u)<<16); }
DI ush f2u(float f){ unsigned int u=__float_as_uint(f); u += 0x7fffu + ((u>>16)&1u); return (ush)(u>>16); }

constexpr int HWc = 4096;
constexpr float RCNT = 1.f/131072.f;      // 1 / (N*H*W)
constexpr size_t BIG = 33554432ull;       // [32][128][4096] bf16 bytes

typedef __attribute__((ext_vector_type(8))) __bf16 bf8;
typedef __attribute__((ext_vector_type(4))) float  f4;

DI void unp8(uint4 q, float* o){
  o[0]=u2f((ush)(q.x&0xffff)); o[1]=u2f((ush)(q.x>>16));
  o[2]=u2f((ush)(q.y&0xffff)); o[3]=u2f((ush)(q.y>>16));
  o[4]=u2f((ush)(q.z&0xffff)); o[5]=u2f((ush)(q.z>>16));
  o[6]=u2f((ush)(q.w&0xffff)); o[7]=u2f((ush)(q.w>>16));
}
DI uint4 pk8(const ush* u){
  uint4 q;
  q.x=(unsigned)u[0]|((unsigned)u[1]<<16); q.y=(unsigned)u[2]|((unsigned)u[3]<<16);
  q.z=(unsigned)u[4]|((unsigned)u[5]<<16); q.w=(unsigned)u[6]|((unsigned)u[7]<<16);
  return q;
}

// ---------------- K0: zero stats + stat shards in one pass -----------------
__global__ void k_zero2(float* __restrict__ a, float* __restrict__ b){
  int i=blockIdx.x*256+threadIdx.x;
  if(i<2048) a[i]=0.f;
  else if(i<2048+49152) b[i-2048]=0.f;
}

// ---------------- fallback: zero-fill output (clean diagnostic failure) ----
__global__ void k_trivial(float* __restrict__ out){
  size_t i=(size_t)blockIdx.x*256+threadIdx.x;
  if(i<16777216ull) out[i]=0.f;
}

// ---------------- K1: per-pixel channel mean/max ---------------------------
__global__ void k_chan_reduce(const float* __restrict__ x, float* __restrict__ smean, float* __restrict__ smax){
  int n = blockIdx.y;
  int px = blockIdx.x*256 + threadIdx.x;
  const float* xp = x + ((size_t)n*128)*HWc + px;
  float s=0.f, m=-INFINITY;
  #pragma unroll 8
  for(int c=0;c<128;c++){ float v=xp[(size_t)c*HWc]; s+=v; m=fmaxf(m,v); }
  smean[n*HWc+px]=s*(1.f/128.f);
  smax[n*HWc+px]=m;
}

// ---------------- K2: 7x7 conv (2->1 ch) + sigmoid -> sa -------------------
__global__ void k_sa(const float* __restrict__ smean, const float* __restrict__ smax,
                     const float* __restrict__ w, float* __restrict__ sa){
  __shared__ float wm[49], wx[49];
  int t=threadIdx.x;
  if(t<49) wm[t]=w[t];
  else if(t<98) wx[t-49]=w[t];
  __syncthreads();
  int n=blockIdx.y;
  int px=blockIdx.x*256+t;
  int r=px>>6, c=px&63;
  const float* pm  = smean + n*HWc;
  const float* pxm = smax  + n*HWc;
  float acc=0.f;
  for(int ky=0;ky<7;ky++){
    int rr=r+ky-3; if(rr<0||rr>=64) continue;
    for(int kx=0;kx<7;kx++){
      int cc=c+kx-3; if(cc<0||cc>=64) continue;
      int q=(rr<<6)+cc;
      acc += wm[ky*7+kx]*pm[q] + wx[ky*7+kx]*pxm[q];
    }
  }
  sa[n*HWc+px] = 1.f/(1.f+expf(-acc));
}

// ---------------- K3: per-(n,c) sum/max over HW of x*sa --------------------
__global__ void k_rowred(const float* __restrict__ x, const float* __restrict__ sa,
                         float* __restrict__ rsum, float* __restrict__ rmax){
  int c=blockIdx.x, n=blockIdx.y;
  const float* xp = x + ((size_t)n*128 + c)*HWc;
  const float* sp = sa + n*HWc;
  float s=0.f, m=-INFINITY;
  for(int i=threadIdx.x;i<HWc;i+=256){
    float v=xp[i]*sp[i]; s+=v; m=fmaxf(m,v);
  }
  __shared__ float ls[4], lm[4];
  for(int o=32;o>0;o>>=1){ s+=__shfl_down(s,o,64); m=fmaxf(m,__shfl_down(m,o,64)); }
  int lane=threadIdx.x&63, wv=threadIdx.x>>6;
  if(lane==0){ ls[wv]=s; lm[wv]=m; }
  __syncthreads();
  if(threadIdx.x==0){
    rsum[n*128+c]=ls[0]+ls[1]+ls[2]+ls[3];
    rmax[n*128+c]=fmaxf(fmaxf(lm[0],lm[1]),fmaxf(lm[2],lm[3]));
  }
}

// ---------------- K4a: channel-attention MLP per n -------------------------
__global__ void k_mlp(const float* __restrict__ rsum, const float* __restrict__ rmax,
                      const float* __restrict__ fc1, const float* __restrict__ fc2,
                      float* __restrict__ att){
  int n=blockIdx.x, t=threadIdx.x;
  __shared__ float zm[128], zx[128], hm[64], hx[64];
  if(t<128){ zm[t]=rsum[n*128+t]*(1.f/4096.f); zx[t]=rmax[n*128+t]; }
  __syncthreads();
  if(t<64){
    float a=0.f;
    for(int c=0;c<128;c++) a+=fc1[t*128+c]*zm[c];
    hm[t]=fmaxf(a,0.f);
  } else if(t<128){
    int j=t-64; float a=0.f;
    for(int c=0;c<128;c++) a+=fc1[j*128+c]*zx[c];
    hx[j]=fmaxf(a,0.f);
  }
  __syncthreads();
  if(t<128){
    float a=0.f,b=0.f;
    for(int j=0;j<64;j++){ float wv=fc2[t*64+j]; a+=wv*hm[j]; b+=wv*hx[j]; }
    att[n*128+t]=1.f/(1.f+expf(-(a+b)));
  }
}

// ---------------- K4b: slist, top-96, num_dict, last-occurrence map --------
__global__ void k_topk(const float* __restrict__ att, const int* __restrict__ perm,
                       int* __restrict__ nd_out, int* __restrict__ dst_pos){
  __shared__ float sl[128];
  __shared__ int nd[128];
  int t=threadIdx.x;          // 128 threads
  float s=0.f;
  for(int n=0;n<32;n++) s+=att[n*128+t];
  sl[t]=s;
  nd[t]=t;
  __syncthreads();
  float v=sl[t]; int r=0;
  for(int c=0;c<128;c++){ float u=sl[c]; r += ((u>v) || (u==v && c<t)) ? 1 : 0; }
  if(r<96) nd[r]=t;
  __syncthreads();
  if(t<32) nd[96+t]=perm[t]&127;
  __syncthreads();
  nd_out[t]=nd[t]&127;
  int pos=-1;
  for(int p=0;p<128;p++) if((nd[p]&127)==t) pos=p;
  dst_pos[t]=pos;
}

// ---------------- zero the halo pad columns of a padded LDS plane ----------
template<int R,int S>
DI void stage_pads(float* __restrict__ Pl, int t){
  if(t<64){
    #pragma unroll
    for(int j=0;j<R;j++) Pl[t*S+j]=0.f;
    #pragma unroll
    for(int j=64+R;j<S;j++) Pl[t*S+j]=0.f;
  }
}

// ---------------- K_cvt6: 6x f32->bf16 weight convert in one launch --------
__global__ void k_cvt6(const float* __restrict__ a,const float* __restrict__ b,
    const float* __restrict__ c,const float* __restrict__ d,
    const float* __restrict__ e,const float* __restrict__ f,
    ush* __restrict__ wb){
  int z=blockIdx.y;
  const float* src = z==0?a:z==1?b:z==2?c:z==3?d:z==4?e:f;
  int i=blockIdx.x*256+threadIdx.x;
  wb[z*16384+i]=f2u(src[i]);
}

// ---------------- K_xtps: xt = bf16(x[nd[p]]*sa*att) + fused poolstats -----
__global__ __launch_bounds__(256) void k_xtps(const float* __restrict__ x,
    const float* __restrict__ sa, const float* __restrict__ att,
    const int* __restrict__ nd, ush* __restrict__ bufX, float* __restrict__ stats){
  constexpr int S=68;
  __shared__ float Pl[64*S];
  int p=blockIdx.x, n=blockIdx.y, t=threadIdx.x;
  int ch=nd[p]&127;
  float a=att[n*128+ch];
  const float* xp=x+((size_t)n*128+ch)*HWc;
  const float* sp=sa+n*HWc;
  int px0=t*16;
  ush u[16];
  #pragma unroll
  for(int j=0;j<4;j++){
    float4 xv=*(const float4*)(xp+px0+4*j);
    float4 sv=*(const float4*)(sp+px0+4*j);
    u[4*j+0]=f2u(xv.x*sv.x*a); u[4*j+1]=f2u(xv.y*sv.y*a);
    u[4*j+2]=f2u(xv.z*sv.z*a); u[4*j+3]=f2u(xv.w*sv.w*a);
  }
  ush* bo=bufX+((size_t)n*128+p)*HWc+px0;
  *(uint4*)bo   = pk8(u);
  *(uint4*)(bo+8)= pk8(u+8);
  float* dst=&Pl[(px0>>6)*S + 1 + (px0&63)];
  #pragma unroll
  for(int i=0;i<16;i++) dst[i]=u2f(u[i]);
  stage_pads<1,S>(Pl,t);
  __syncthreads();
  int r=t>>2, c0=(t&3)*16;
  float s[16], m[16];
  #pragma unroll
  for(int i=0;i<16;i++){ s[i]=0.f; m[i]=-INFINITY; }
  int rin=0;
  #pragma unroll
  for(int ky=-1;ky<=1;ky++){
    int rr=r+ky;
    if(rr<0||rr>=64) continue;
    rin++;
    float row[20];
    #pragma unroll
    for(int j=0;j<5;j++) *(float4*)&row[4*j] = *(const float4*)&Pl[rr*S + c0 + 4*j];
    float e0  = (c0==0)  ? -INFINITY : row[0];
    float e17 = (c0==48) ? -INFINITY : row[17];
    #pragma unroll
    for(int i=0;i<16;i++){
      float lf = (i==0)  ? e0  : row[i];
      float rg = (i==15) ? e17 : row[i+2];
      s[i] += row[i]+row[i+1]+row[i+2];
      m[i] = fmaxf(m[i], fmaxf(lf, fmaxf(row[i+1], rg)));
    }
  }
  float sm=0,qm=0,sv=0,qv=0;
  #pragma unroll
  for(int i=0;i<16;i++){
    int c=c0+i;
    float cnt=(float)(rin*(3-(c==0)-(c==63)));
    float ap=s[i]/cnt, mp=m[i];
    sm+=mp; qm+=mp*mp; sv+=ap; qv+=ap*ap;
  }
  for(int o=32;o>0;o>>=1){
    sm+=__shfl_down(sm,o,64); qm+=__shfl_down(qm,o,64);
    sv+=__shfl_down(sv,o,64); qv+=__shfl_down(qv,o,64);
  }
  __shared__ float l[4][4];
  int lane=t&63, wv=t>>6;
  if(lane==0){ l[wv][0]=sm; l[wv][1]=qm; l[wv][2]=sv; l[wv][3]=qv; }
  __syncthreads();
  if(t==0){
    atomicAdd(&stats[p],     l[0][0]+l[1][0]+l[2][0]+l[3][0]);
    atomicAdd(&stats[128+p], l[0][1]+l[1][1]+l[2][1]+l[3][1]);
    atomicAdd(&stats[256+p], l[0][2]+l[1][2]+l[2][2]+l[3][2]);
    atomicAdd(&stats[384+p], l[0][3]+l[1][3]+l[2][3]+l[3][3]);
  }
}

// ---------------- dw core: depthwise conv on one bf16 (n,p) plane ----------
template<int KS,int DIL,int BN>
DI void dw_core(float* Pl, const ush* src, const float* __restrict__ dww,
                const float* __restrict__ fin, int p,int n,int t, ush* outb){
  constexpr int R=(KS/2)*DIL;          // halo reach: 1,2,2,4
  constexpr int S=(R==4)?76:68;        // stride = 4 mod 32, 16B-aligned
  constexpr int NL=(16+2*R+3)/4;       // float4 loads per row (5 or 6)
  float mean=0.f, rstd=0.f;
  if constexpr(BN){ mean=fin[p]; rstd=fin[128+p]; }
  const ush* bp = src + ((size_t)n*128+p)*HWc;
  int px0=t*16;
  uint4 va=*(const uint4*)(bp+px0);
  uint4 vb=*(const uint4*)(bp+px0+8);
  float* dst=&Pl[(px0>>6)*S + R + (px0&63)];
  unsigned int wv8[8]={va.x,va.y,va.z,va.w,vb.x,vb.y,vb.z,vb.w};
  #pragma unroll
  for(int j=0;j<8;j++){
    float v0=u2f((ush)(wv8[j]&0xffff)), v1=u2f((ush)(wv8[j]>>16));
    if constexpr(BN){ v0=(v0-mean)*rstd; v1=(v1-mean)*rstd; }
    dst[2*j]  =fmaxf(v0,0.f);
    dst[2*j+1]=fmaxf(v1,0.f);
  }
  stage_pads<R,S>(Pl,t);
  __syncthreads();
  float wk[KS*KS];
  #pragma unroll
  for(int i=0;i<KS*KS;i++) wk[i]=dww[p*KS*KS+i];
  int r=t>>2, c0=(t&3)*16;
  float acc[16];
  #pragma unroll
  for(int i=0;i<16;i++) acc[i]=0.f;
  #pragma unroll
  for(int ky=0;ky<KS;ky++){
    int rr=r+(ky-KS/2)*DIL;
    if(rr<0||rr>=64) continue;
    float row[NL*4];
    #pragma unroll
    for(int j=0;j<NL;j++) *(float4*)&row[4*j] = *(const float4*)&Pl[rr*S + c0 + 4*j];
    #pragma unroll
    for(int kx=0;kx<KS;kx++){
      float wv=wk[ky*KS+kx];
      #pragma unroll
      for(int i=0;i<16;i++) acc[i]+=wv*row[R + i + (kx-KS/2)*DIL];
    }
  }
  ush* op = outb + ((size_t)n*128+p)*HWc + r*64 + c0;
  #pragma unroll
  for(int q=0;q<4;q++){
    ushort4 vv;
    vv.x=f2u(acc[4*q+0]); vv.y=f2u(acc[4*q+1]);
    vv.z=f2u(acc[4*q+2]); vv.w=f2u(acc[4*q+3]);
    *(ushort4*)(op+4*q)=vv;
  }
}

// ---------------- K_dw4: all four first-stage depthwise convs, z-batched ---
__global__ __launch_bounds__(256) void k_dw4(const ush* __restrict__ bufX,
    const float* __restrict__ s3d1,const float* __restrict__ s5d1,
    const float* __restrict__ d3dw,const float* __restrict__ d5dw,
    ush* __restrict__ bufA, ush* __restrict__ bufB,
    ush* __restrict__ bufC, ush* __restrict__ bufD){
  __shared__ float Pl[64*76];
  int p=blockIdx.x,n=blockIdx.y,t=threadIdx.x,z=blockIdx.z;
  if(z==0)      dw_core<3,1,0>(Pl,bufX,s3d1,nullptr,p,n,t,bufA);
  else if(z==1) dw_core<5,1,0>(Pl,bufX,s5d1,nullptr,p,n,t,bufB);
  else if(z==2) dw_core<3,2,0>(Pl,bufX,d3dw,nullptr,p,n,t,bufC);
  else          dw_core<5,2,0>(Pl,bufX,d5dw,nullptr,p,n,t,bufD);
}

// ---------------- K_dw2: second-stage depthwise (bn+relu), z-batched, in-place
__global__ __launch_bounds__(256) void k_dw2(ush* bufA, ush* bufB,
    const float* __restrict__ s3d2,const float* __restrict__ s5d2,
    const float* __restrict__ fin0,const float* __restrict__ fin2){
  __shared__ float Pl[64*68];
  int p=blockIdx.x,n=blockIdx.y,t=threadIdx.x,z=blockIdx.z;
  if(z==0) dw_core<3,1,1>(Pl,bufA,s3d2,fin0,p,n,t,bufA);
  else     dw_core<5,1,1>(Pl,bufB,s5d2,fin2,p,n,t,bufB);
}

// ---------------- pw core: persistent multi-window MFMA GEMM + bn stats ----
// D[co][px] = sum_ci W[co][ci]*in[ci][px]. m92/m97-verified fragment layouts.
// Block owns 4 windows of 128 px (512 px total): 256 B/ci-row per staging
// burst (2x round 8) to cut DRAM row-activate cost; A-frags reloaded per-kt
// (16 VGPR not 64); Lf epilogue with full-line stores. IN-PLACE SAFE.
DI void pw_core(char* pool, const ush* dwin, const ush* __restrict__ wt,
                ush* outb, float* __restrict__ shad, int bx,int by,int t){
  ush (*Bt)[132] = (ush(*)[132])pool;   // 128 px x 132 ush = 33792 B
  float* Lf = (float*)pool;             // 64 co x 130 f32 = 33280 B (aliased)
  int n=by;
  int lane=t&63, wv=t>>6;
  int co0=(wv>>1)*64, pxh=(wv&1)*64;    // wave tile: 64 co x 64 px
  int g=lane>>4, sl=lane&15;
  int acg = g*8;
  float* sh = shad + (((bx + by)&31)*256);

  for(int w=0;w<4;w++){
    int px0 = (bx*4 + w)*128;
    const ush* dp = dwin + ((size_t)n*128)*HWc + px0;
    // stage 128 ci x 128 px: e in [0,2048): ci-pair c2=e>>5, px quarter (e&31)*4
    #pragma unroll
    for(int k=0;k<8;k++){
      int e = t + k*256;
      int c2 = e>>5;                   // 0..63
      int p4 = (e&31)*4;               // 0..124
      const ush* g0 = dp + (size_t)(2*c2)*HWc + p4;
      ushort4 va = *(const ushort4*)g0;
      ushort4 vb = *(const ushort4*)(g0 + HWc);
      *(unsigned int*)&Bt[p4+0][2*c2] = (unsigned int)va.x | ((unsigned int)vb.x<<16);
      *(unsigned int*)&Bt[p4+1][2*c2] = (unsigned int)va.y | ((unsigned int)vb.y<<16);
      *(unsigned int*)&Bt[p4+2][2*c2] = (unsigned int)va.z | ((unsigned int)vb.z<<16);
      *(unsigned int*)&Bt[p4+3][2*c2] = (unsigned int)va.w | ((unsigned int)vb.w<<16);
    }
    __syncthreads();
    f4 acc[4][4] = {};
    #pragma unroll
    for(int kt=0;kt<4;kt++){
      bf8 ak[4];
      #pragma unroll
      for(int mt=0;mt<4;mt++)
        ak[mt] = *(const bf8*)(wt + (size_t)(co0+mt*16+sl)*128 + kt*32 + acg);
      #pragma unroll
      for(int nt=0;nt<4;nt++){
        union { uint2 h[2]; bf8 v; } u;
        const ush* bp = &Bt[pxh + nt*16 + sl][kt*32 + acg];
        u.h[0] = *(const uint2*)bp;
        u.h[1] = *(const uint2*)(bp+4);
        #pragma unroll
        for(int mt=0;mt<4;mt++)
          acc[mt][nt] = __builtin_amdgcn_mfma_f32_16x16x32_bf16(ak[mt], u.v, acc[mt][nt], 0,0,0);
      }
    }
    __syncthreads();                   // Bt dead
    // epilogue: two co-half passes through Lf
    #pragma unroll
    for(int h=0;h<2;h++){
      if((wv>>1)==h){
        #pragma unroll
        for(int mt=0;mt<4;mt++)
          #pragma unroll
          for(int r=0;r<4;r++){
            int lco = mt*16 + g*4 + r;
            #pragma unroll
            for(int nt=0;nt<4;nt++)
              Lf[lco*130 + pxh + nt*16 + sl] = acc[mt][nt][r];
          }
      }
      __syncthreads();
      {
        int lco=t>>2, q=t&3;
        const float* Lr = &Lf[lco*130 + q*32];
        float s1=0.f, s2=0.f;
        ush ob16[32];
        #pragma unroll
        for(int j=0;j<16;j++){
          float2 v=*(const float2*)(Lr+2*j);
          s1+=v.x+v.y; s2+=v.x*v.x+v.y*v.y;
          ob16[2*j]=f2u(v.x); ob16[2*j+1]=f2u(v.y);
        }
        s1+=__shfl_xor(s1,1,64); s2+=__shfl_xor(s2,1,64);
        s1+=__shfl_xor(s1,2,64); s2+=__shfl_xor(s2,2,64);
        int co = h*64 + lco;
        ush* op = outb + ((size_t)n*128+co)*HWc + px0 + q*32;
        *(uint4*)op      = pk8(ob16);
        *(uint4*)(op+8)  = pk8(ob16+8);
        *(uint4*)(op+16) = pk8(ob16+16);
        *(uint4*)(op+24) = pk8(ob16+24);
        if(q==0){ atomicAdd(&sh[co],s1); atomicAdd(&sh[128+co],s2); }
      }
      __syncthreads();
    }
  }
}

// ---------------- K_pwm: z-batched persistent pointwise MFMA ---------------
__global__ __launch_bounds__(256) void k_pwm(ush* bA, ush* bB, ush* bC, ush* bD,
    const ush* __restrict__ w0,const ush* __restrict__ w1,
    const ush* __restrict__ w2,const ush* __restrict__ w3,
    float* __restrict__ s0,float* __restrict__ s1,
    float* __restrict__ s2,float* __restrict__ s3){
  __shared__ __align__(16) char pool[33792];
  int z=blockIdx.z;
  ush* b = z==0?bA:z==1?bB:z==2?bC:bD;
  const ush* wt = z==0?w0:z==1?w1:z==2?w2:w3;
  float* sh = z==0?s0:z==1?s1:z==2?s2:s3;
  pw_core(pool,b,wt,b,sh,blockIdx.x,blockIdx.y,threadIdx.x);
}

// ---------------- K_statfin: fold 32 shards -> mean/rstd (z-batched) -------
__global__ void k_statfin4(const float* __restrict__ s0,const float* __restrict__ s1,
    const float* __restrict__ s2,const float* __restrict__ s3,
    float* __restrict__ f0,float* __restrict__ f1,
    float* __restrict__ f2,float* __restrict__ f3){
  int z=blockIdx.x, t=threadIdx.x;
  const float* shd = z==0?s0:z==1?s1:z==2?s2:s3;
  float* fin = z==0?f0:z==1?f1:z==2?f2:f3;
  if(t<128){
    float su=0.f, sq=0.f;
    #pragma unroll
    for(int j=0;j<32;j++){ su+=shd[j*256+t]; sq+=shd[j*256+128+t]; }
    float mean=su*RCNT, var=sq*RCNT-mean*mean;
    fin[t]=mean;
    fin[128+t]=rsqrtf(var+1e-5f);
  }
}

// ---------------- K_bacc: fused base + all four branch accumulates ---------
__global__ __launch_bounds__(256) void k_bacc(const float* __restrict__ x,
    const float* __restrict__ sa, const float* __restrict__ att,
    const int* __restrict__ nd, const int* __restrict__ dpos,
    const float* __restrict__ stats,
    const float* __restrict__ fin1,const float* __restrict__ fin3,
    const float* __restrict__ fin4,const float* __restrict__ fin5,
    const float* __restrict__ wts, const ush* __restrict__ bufX,
    const ush* __restrict__ brA,const ush* __restrict__ brB,
    const ush* __restrict__ brC,const ush* __restrict__ brD,
    float* __restrict__ out){
  constexpr int S=68;
  __shared__ float Pl[64*S];
  int ch=blockIdx.x, n=blockIdx.y, t=threadIdx.x;
  int p=dpos[ch];                      // block-uniform branch
  if(p<0){
    float a=att[n*128+ch];
    const float* xp=x+((size_t)n*128+ch)*HWc;
    const float* sp=sa+n*HWc;
    float* op=out+((size_t)n*128+ch)*HWc;
    int px0=t*16;
    #pragma unroll
    for(int j=0;j<4;j++){
      float4 xv=*(const float4*)(xp+px0+4*j);
      float4 sv=*(const float4*)(sp+px0+4*j);
      float4 ov;
      ov.x=xv.x*sv.x*a; ov.y=xv.y*sv.y*a; ov.z=xv.z*sv.z*a; ov.w=xv.w*sv.w*a;
      *(float4*)(op+px0+4*j)=ov;
    }
    return;
  }
  // stage xt plane (bf16) from bufX
  const ush* bxp=bufX+((size_t)n*128+p)*HWc;
  int px0=t*16;
  uint4 qa=*(const uint4*)(bxp+px0), qb=*(const uint4*)(bxp+px0+8);
  {
    float tv[16];
    unp8(qa,tv); unp8(qb,tv+8);
    float* dst=&Pl[(px0>>6)*S + 1 + (px0&63)];
    #pragma unroll
    for(int i=0;i<16;i++) dst[i]=tv[i];
  }
  stage_pads<1,S>(Pl,t);
  __syncthreads();
  float w1=wts[1],w2=wts[2],w3=wts[3],w4=wts[4],w5=wts[5],w6=wts[6],w7=wts[7];
  float m0,r0v,m1,r1v;
  { float su=stats[p],     sq=stats[128+p]; float mean=su*RCNT,var=sq*RCNT-mean*mean; m0=mean; r0v=rsqrtf(var+1e-5f); }
  { float su=stats[256+p], sq=stats[384+p]; float mean=su*RCNT,var=sq*RCNT-mean*mean; m1=mean; r1v=rsqrtf(var+1e-5f); }
  float mA=fin1[p],rA=fin1[128+p], mB=fin3[p],rB=fin3[128+p];
  float mC=fin4[p],rC=fin4[128+p], mD=fin5[p],rD=fin5[128+p];
  int r=t>>2, c0=(t&3)*16;
  float s[16], m[16], crow[16];
  #pragma unroll
  for(int i=0;i<16;i++){ s[i]=0.f; m[i]=-INFINITY; }
  int rin=0;
  #pragma unroll
  for(int ky=-1;ky<=1;ky++){
    int rr=r+ky;
    if(rr<0||rr>=64) continue;
    rin++;
    float row[20];
    #pragma unroll
    for(int j=0;j<5;j++) *(float4*)&row[4*j] = *(const float4*)&Pl[rr*S + c0 + 4*j];
    if(ky==0){
      #pragma unroll
      for(int i=0;i<16;i++) crow[i]=row[i+1];
    }
    float e0  = (c0==0)  ? -INFINITY : row[0];
    float e17 = (c0==48) ? -INFINITY : row[17];
    #pragma unroll
    for(int i=0;i<16;i++){
      float lf = (i==0)  ? e0  : row[i];
      float rg = (i==15) ? e17 : row[i+2];
      s[i] += row[i]+row[i+1]+row[i+2];
      m[i] = fmaxf(m[i], fmaxf(lf, fmaxf(row[i+1], rg)));
    }
  }
  float vout[16];
  #pragma unroll
  for(int i=0;i<16;i++){
    int c=c0+i;
    float cnt=(float)(rin*(3-(c==0)-(c==63)));
    float ap=s[i]/cnt;
    vout[i] = w3*crow[i] + w1*(m[i]-m0)*r0v + w2*(ap-m1)*r1v;
  }
  size_t boff=((size_t)n*128+p)*HWc + r*64 + c0;
  {
    float tv[16];
    unp8(*(const uint4*)(brA+boff),tv); unp8(*(const uint4*)(brA+boff+8),tv+8);
    #pragma unroll
    for(int i=0;i<16;i++) vout[i]+=w4*(tv[i]-mA)*rA;
    unp8(*(const uint4*)(brB+boff),tv); unp8(*(const uint4*)(brB+boff+8),tv+8);
    #pragma unroll
    for(int i=0;i<16;i++) vout[i]+=w5*(tv[i]-mB)*rB;
    unp8(*(const uint4*)(brC+boff),tv); unp8(*(const uint4*)(brC+boff+8),tv+8);
    #pragma unroll
    for(int i=0;i<16;i++) vout[i]+=w6*(tv[i]-mC)*rC;
    unp8(*(const uint4*)(brD+boff),tv); unp8(*(const uint4*)(brD+boff+8),tv+8);
    #pragma unroll
    for(int i=0;i<16;i++) vout[i]+=w7*(tv[i]-mD)*rD;
  }
  float* op=out+((size_t)n*128+ch)*HWc + r*64 + c0;
  #pragma unroll
  for(int q=0;q<4;q++) *(float4*)(op+4*q)=*(float4*)&vout[4*q];
}

extern "C" void kernel_launch(void* const* d_in, const int* in_sizes, int n_in,
                              void* d_out, int out_size, void* d_ws, size_t ws_size,
                              hipStream_t stream){
  (void)in_sizes; (void)n_in; (void)out_size;
  const float* x   =(const float*)d_in[0];
  const float* wts =(const float*)d_in[1];
  const float* fc1 =(const float*)d_in[2];
  const float* fc2 =(const float*)d_in[3];
  const float* saw =(const float*)d_in[4];
  const float* s3d1=(const float*)d_in[5];
  const float* s3p1=(const float*)d_in[6];
  const float* s3d2=(const float*)d_in[7];
  const float* s3p2=(const float*)d_in[8];
  const float* s5d1=(const float*)d_in[9];
  const float* s5p1=(const float*)d_in[10];
  const float* s5d2=(const float*)d_in[11];
  const float* s5p2=(const float*)d_in[12];
  const float* d3dw=(const float*)d_in[13];
  const float* d3pw=(const float*)d_in[14];
  const float* d5dw=(const float*)d_in[15];
  const float* d5pw=(const float*)d_in[16];
  const int* perm=(const int*)d_in[17];
  float* out=(float*)d_out;

  char* w=(char*)d_ws;
  float* stats=(float*)w;  w+=8192;
  float* smean=(float*)w;  w+=524288;
  float* smax =(float*)w;  w+=524288;
  float* sa   =(float*)w;  w+=524288;
  float* rsum =(float*)w;  w+=16384;
  float* rmax =(float*)w;  w+=16384;
  float* att  =(float*)w;  w+=16384;
  int*   nd   =(int*)w;    w+=512;
  int*   dpos =(int*)w;    w+=512;
  size_t small_bytes=(size_t)(w-(char*)d_ws);    // 1631232
  ush* bufA=(ush*)w;
  ush* bufB=(ush*)(w+BIG);
  ush* bufC=(ush*)(w+2*BIG);
  ush* bufD=(ush*)(w+3*BIG);
  ush* bufX=(ush*)(w+4*BIG);

  if(ws_size < small_bytes + 5*BIG){
    k_trivial<<<dim3(65536),dim3(256),0,stream>>>(out);
    return;
  }

  // bf16 pw weights in smean region (dead after k_sa). 6 x 32KB.
  ush* wb=(ush*)smean;
  ush* wb_s3p1=wb;
  ush* wb_s3p2=wb+16384;
  ush* wb_s5p1=wb+32768;
  ush* wb_s5p2=wb+49152;
  ush* wb_d3pw=wb+65536;
  ush* wb_d5pw=wb+81920;

  // 32-way sharded bn-stat accumulators in smax (dead after k_sa).
  float* shd0=smax;            // s3p1 (sep3 mid)
  float* shd1=smax+ 8192;      // s3p2 (sep3 final)
  float* shd2=smax+16384;      // s5p1 (sep5 mid)
  float* shd3=smax+24576;      // s5p2 (sep5 final)
  float* shd4=smax+32768;      // d3pw (dil3)
  float* shd5=smax+40960;      // d5pw (dil5)

  // finalized mean/rstd tables in the stats block
  float* fin0=stats+ 512;
  float* fin1=stats+ 768;
  float* fin2=stats+1024;
  float* fin3=stats+1280;
  float* fin4=stats+1536;
  float* fin5=stats+1792;

  dim3 B(256);
  dim3 Gpn(128,32);
  k_chan_reduce<<<dim3(16,32),B,0,stream>>>(x,smean,smax);
  k_sa<<<dim3(16,32),B,0,stream>>>(smean,smax,saw,sa);
  // smean/smax dead -> zero stats+shards, convert weights
  k_zero2<<<dim3(200),B,0,stream>>>(stats,smax);
  k_cvt6<<<dim3(64,6),B,0,stream>>>(s3p1,s3p2,s5p1,s5p2,d3pw,d5pw,wb);
  k_rowred<<<dim3(128,32),B,0,stream>>>(x,sa,rsum,rmax);
  k_mlp<<<dim3(32),B,0,stream>>>(rsum,rmax,fc1,fc2,att);
  k_topk<<<dim3(1),dim3(128),0,stream>>>(att,perm,nd,dpos);
  // xt materialize + fused poolstats
  k_xtps<<<Gpn,B,0,stream>>>(x,sa,att,nd,bufX,stats);
  // all four branch dw1 -> pw1 -> statfin
  k_dw4<<<dim3(128,32,4),B,0,stream>>>(bufX,s3d1,s5d1,d3dw,d5dw,bufA,bufB,bufC,bufD);
  k_pwm<<<dim3(8,32,4),B,0,stream>>>(bufA,bufB,bufC,bufD,
      wb_s3p1,wb_s5p1,wb_d3pw,wb_d5pw, shd0,shd2,shd4,shd5);
  k_statfin4<<<dim3(4),dim3(128),0,stream>>>(shd0,shd2,shd4,shd5,fin0,fin2,fin4,fin5);
  // sep second stage (in-place in bufA/bufB)
  k_dw2<<<dim3(128,32,2),B,0,stream>>>(bufA,bufB,s3d2,s5d2,fin0,fin2);
  k_pwm<<<dim3(8,32,2),B,0,stream>>>(bufA,bufB,bufA,bufA,
      wb_s3p2,wb_s5p2,wb_s3p2,wb_s3p2, shd1,shd3,shd1,shd1);
  k_statfin4<<<dim3(2),dim3(128),0,stream>>>(shd1,shd3,shd1,shd1,fin1,fin3,fin1,fin1);
  // fused base + 4-branch accumulate: single write of out
  k_bacc<<<Gpn,B,0,stream>>>(x,sa,att,nd,dpos,stats,fin1,fin3,fin4,fin5,
      wts,bufX,bufA,bufB,bufC,bufD,out);
}